// Round 16
// baseline (568.503 us; speedup 1.0000x reference)
//
#include <hip/hip_runtime.h>

// ---------------------------------------------------------------------------
// NucleusMoEImageTransformerBlock round 16.
// B=2 SI=1024 ST=512 D=2048 H=16 KV=4 HD=128 E=8 F=1024 TOPK=2
// Round-16: heterogeneous-grid fusion -- attention (blocks 0..255) and the
// wo/gate_up/down weight conversion (blocks 256+) share ONE kernel, so the
// ~330MB of convert traffic streams under attention's compute (attn runs at
// 2% HBM, 1 blk/CU). Up-front convert shrinks to wqkv/wkvt only (~50MB).
// Convert body reverted to the empirically-best v1 (64x64, stride-66 LDS).
// Everything else unchanged from r14/r15.
// ---------------------------------------------------------------------------

typedef __attribute__((ext_vector_type(8))) __bf16 bf16x8;
typedef __attribute__((ext_vector_type(8))) unsigned short u16x8;
typedef __attribute__((ext_vector_type(4))) unsigned short u16x4;
typedef __attribute__((ext_vector_type(4))) float f32x4;

__device__ __forceinline__ unsigned short f2bf(float x) {
  unsigned u = __builtin_bit_cast(unsigned, x);
  u += 0x7fffu + ((u >> 16) & 1u);        // RNE
  return (unsigned short)(u >> 16);
}
__device__ __forceinline__ float bf2f(unsigned short b) {
  return __builtin_bit_cast(float, ((unsigned)b) << 16);
}

__device__ __forceinline__ void glds16(const unsigned short* g, unsigned short* l) {
  __builtin_amdgcn_global_load_lds(
      (const __attribute__((address_space(1))) void*)g,
      (__attribute__((address_space(3))) void*)l, 16, 0, 0);
}

// m204 bijective XCD chunk swizzle.
__device__ __forceinline__ int xcd_swz(int orig, int nwg) {
  int q = nwg >> 3, r = nwg & 7;
  int xcd = orig & 7, idx = orig >> 3;
  int base = (xcd < r) ? xcd * (q + 1) : r * (q + 1) + (xcd - r) * q;
  return base + idx;
}

struct CvtJobs {
  const float* src[8];
  unsigned short* dst[8];
  int K[8];
  int N[8];
  int off[9];
};

// ---------------------------------------------------------------------------
// Small up-front convert (v1 body, 256 threads): wqkv + wkvt weights only.
// ---------------------------------------------------------------------------
__global__ __launch_bounds__(256) void convert_small(CvtJobs jb)
{
  __shared__ unsigned short T[64][66];
  const int bid = blockIdx.x;
  int j = 0;
  #pragma unroll
  for (int i = 0; i < 8; ++i) if (bid >= jb.off[i + 1]) j = i + 1;
  const int local = bid - jb.off[j];
  const int K = jb.K[j], N = jb.N[j];
  const int kb = K >> 6, nb = N >> 6;
  const int kt = local % kb;
  const int rest = local / kb;
  const int nt = rest % nb, zi = rest / nb;
  const float* Wz = jb.src[j] + (size_t)zi * K * N;
  unsigned short* WTz = jb.dst[j] + (size_t)zi * K * N;
  const int k0 = kt * 64, n0 = nt * 64;
  const int tid = threadIdx.x;
  #pragma unroll
  for (int i = tid; i < 64 * 16; i += 256) {
    int k = i >> 4, n4 = (i & 15) * 4;
    float4 v = *(const float4*)&Wz[(size_t)(k0 + k) * N + n0 + n4];
    T[n4 + 0][k] = f2bf(v.x);
    T[n4 + 1][k] = f2bf(v.y);
    T[n4 + 2][k] = f2bf(v.z);
    T[n4 + 3][k] = f2bf(v.w);
  }
  __syncthreads();
  #pragma unroll
  for (int i = tid; i < 64 * 8; i += 256) {
    int n = i >> 3, k8 = (i & 7) * 8;
    *(u16x8*)&WTz[(size_t)(n0 + n) * K + k0 + k8] = *(const u16x8*)&T[n][k8];
  }
}

// ---------------------------------------------------------------------------
// Epilogue argument bundle for gemm_bb modes 1/2.
// ---------------------------------------------------------------------------
struct Epi {
  unsigned short* qb;
  unsigned short* kbuf;
  unsigned short* vbuf;
  const float* q_nw;
  const float* k_nw;
  const float* kt_nw;
  const float* icos;
  const float* isin;
  const float* tcos;
  const float* tsin;
  float scale;
};

// ---------------------------------------------------------------------------
// Dense GEMM (modes as r13): 128x128 tile, counted-vmcnt dbuf pipeline.
// ---------------------------------------------------------------------------
__global__ __launch_bounds__(256) void gemm_bb(
    const unsigned short* __restrict__ A, const unsigned short* __restrict__ BT,
    float* __restrict__ C, const float* __restrict__ resid,
    int M, int N, int K, int mode, Epi ep)
{
  __shared__ unsigned short As[2][128 * 64];
  __shared__ unsigned short Bs[2][128 * 64];
  const int mb = M >> 7;
  const int w = xcd_swz(blockIdx.x, gridDim.x);
  const int bm = (w % mb) * 128, bn = (w / mb) * 128;
  const int tid = threadIdx.x, lane = tid & 63, wid = tid >> 6;
  const int wm = (wid >> 1) * 64, wn = (wid & 1) * 64;
  const int l16 = lane & 15, g4 = lane >> 4;
  const int rseg = lane >> 3;
  const int csw  = ((lane & 7) ^ rseg) * 8;
  const unsigned short* aSrc[4];
  const unsigned short* bSrc[4];
  #pragma unroll
  for (int p = 0; p < 4; ++p) {
    int row = (p * 4 + wid) * 8 + rseg;
    aSrc[p] = A  + (size_t)(bm + row) * K + csw;
    bSrc[p] = BT + (size_t)(bn + row) * K + csw;
  }
  f32x4 acc[4][4] = {};
  const int NT = K >> 6;
  #pragma unroll
  for (int p = 0; p < 4; ++p) glds16(aSrc[p], &As[0][(p * 4 + wid) * 512]);
  #pragma unroll
  for (int p = 0; p < 4; ++p) glds16(bSrc[p], &Bs[0][(p * 4 + wid) * 512]);
  for (int t = 0; t < NT; ++t) {
    const int cur = t & 1;
    if (t + 1 < NT) {
      const int k0 = (t + 1) << 6;
      #pragma unroll
      for (int p = 0; p < 4; ++p) glds16(aSrc[p] + k0, &As[cur ^ 1][(p * 4 + wid) * 512]);
      #pragma unroll
      for (int p = 0; p < 4; ++p) glds16(bSrc[p] + k0, &Bs[cur ^ 1][(p * 4 + wid) * 512]);
      asm volatile("s_waitcnt vmcnt(8)" ::: "memory");
    } else {
      asm volatile("s_waitcnt vmcnt(0)" ::: "memory");
    }
    __builtin_amdgcn_s_barrier();
    __builtin_amdgcn_sched_barrier(0);
    const unsigned short* ab = &As[cur][0];
    const unsigned short* bb = &Bs[cur][0];
    #pragma unroll
    for (int ks = 0; ks < 2; ++ks) {
      bf16x8 af[4], bf[4];
      #pragma unroll
      for (int i = 0; i < 4; ++i) {
        int ra = wm + i * 16 + l16;
        int rb = wn + i * 16 + l16;
        int ch = ((ks * 4 + g4) ^ (l16 & 7)) * 8;
        af[i] = *(const bf16x8*)&ab[ra * 64 + ch];
        bf[i] = *(const bf16x8*)&bb[rb * 64 + ch];
      }
      #pragma unroll
      for (int mi = 0; mi < 4; ++mi)
        #pragma unroll
        for (int ni = 0; ni < 4; ++ni)
          acc[mi][ni] = __builtin_amdgcn_mfma_f32_16x16x32_bf16(af[mi], bf[ni], acc[mi][ni], 0, 0, 0);
    }
    __builtin_amdgcn_sched_barrier(0);
    __builtin_amdgcn_s_barrier();
  }
  const int r4 = g4 * 4;

  if (mode == 0) {
    #pragma unroll
    for (int mi = 0; mi < 4; ++mi)
      #pragma unroll
      for (int ni = 0; ni < 4; ++ni)
        #pragma unroll
        for (int r = 0; r < 4; ++r) {
          int row = bm + wm + mi * 16 + r4 + r;
          int col = bn + wn + ni * 16 + l16;
          float v = acc[mi][ni][r];
          if (resid) v += resid[(size_t)row * N + col];
          C[(size_t)row * N + col] = v;
        }
    return;
  }

  // ---- fused head-norm / rope / relayout epilogue (modes 1,2) ----
  const int bt = bn >> 7;
  unsigned short* dst;
  const float* nw = nullptr;
  const float* cosT = nullptr;
  const float* sinT = nullptr;
  int h, NH, st, soff, vkind = 0, shift;
  float premul = 1.f;
  int S;
  if (mode == 1) {
    S = 1024; shift = 10;
    if (bt < 16)      { h = bt;      dst = ep.qb;   nw = ep.q_nw; cosT = ep.icos; sinT = ep.isin;
                        NH = 16; st = 1024; soff = 0; premul = ep.scale; }
    else if (bt < 20) { h = bt - 16; dst = ep.kbuf; nw = ep.k_nw; cosT = ep.icos; sinT = ep.isin;
                        NH = 4;  st = 1536; soff = 0; }
    else              { h = bt - 20; dst = ep.vbuf; vkind = 1; NH = 4; st = 1536; soff = 0; }
  } else {
    S = 512; shift = 9;
    if (bt < 4) { h = bt;     dst = ep.kbuf; nw = ep.kt_nw; cosT = ep.tcos; sinT = ep.tsin;
                  NH = 4; st = 1536; soff = 1024; }
    else        { h = bt - 4; dst = ep.vbuf; vkind = 1; NH = 4; st = 1536; soff = 1024; }
  }

  if (vkind) {
    #pragma unroll
    for (int mi = 0; mi < 4; ++mi)
      #pragma unroll
      for (int ni = 0; ni < 4; ++ni)
        #pragma unroll
        for (int r = 0; r < 4; ++r) {
          int row = wm + mi * 16 + r4 + r;
          int d   = wn + ni * 16 + l16;
          int token = bm + row;
          int srow = token & (S - 1), bidx = token >> shift;
          dst[((size_t)(bidx * NH + h) * st + srow + soff) * 128 + d] = f2bf(acc[mi][ni][r]);
        }
    return;
  }

  float* ssb = (float*)&As[0][0];
  float ssp[4][4];
  #pragma unroll
  for (int mi = 0; mi < 4; ++mi)
    #pragma unroll
    for (int r = 0; r < 4; ++r) {
      float v = 0.f;
      #pragma unroll
      for (int ni = 0; ni < 4; ++ni) v += acc[mi][ni][r] * acc[mi][ni][r];
      #pragma unroll
      for (int off = 1; off < 16; off <<= 1) v += __shfl_xor(v, off);
      ssp[mi][r] = v;
    }
  __syncthreads();
  if (l16 == 0) {
    #pragma unroll
    for (int mi = 0; mi < 4; ++mi)
      #pragma unroll
      for (int r = 0; r < 4; ++r)
        ssb[(wid & 1) * 128 + wm + mi * 16 + r4 + r] = ssp[mi][r];
  }
  __syncthreads();
  #pragma unroll
  for (int mi = 0; mi < 4; ++mi)
    #pragma unroll
    for (int r = 0; r < 4; ++r) {
      int row = wm + mi * 16 + r4 + r;
      float tot = ssb[row] + ssb[128 + row];
      float inv = rsqrtf(tot * (1.f / 128.f) + 1e-6f);
      int token = bm + row;
      int srow = token & (S - 1), bidx = token >> shift;
      #pragma unroll
      for (int ni = 0; ni < 4; ++ni) {
        int d = wn + ni * 16 + l16;
        float y = acc[mi][ni][r] * inv * nw[d];
        float part = __shfl_xor(y, 1);
        float c  = cosT[srow * 64 + (d >> 1)];
        float sn = sinT[srow * 64 + (d >> 1)];
        float outv = (d & 1) ? (part * sn + y * c) : (y * c - part * sn);
        dst[((size_t)(bidx * NH + h) * st + srow + soff) * 128 + d] = f2bf(outv * premul);
      }
    }
}

// ---------------------------------------------------------------------------
// Expert-batched MoE GEMM, 256x256, split-K=2, counted-vmcnt dbuf, bf16 out.
// ---------------------------------------------------------------------------
__global__ __launch_bounds__(512, 1) void gemm_moe_256sk(
    const unsigned short* __restrict__ A, const unsigned short* __restrict__ BTall,
    unsigned short* __restrict__ C0, unsigned short* __restrict__ C1,
    const int* __restrict__ counts, const int* __restrict__ offsets,
    const int* __restrict__ pair_token, const unsigned short* __restrict__ zbuf,
    int gather, int K, int N)
{
  const int w = xcd_swz(blockIdx.x, gridDim.x);
  const int e = w >> 7;
  const int local = w & 127;
  const int bm = ((local >> 4) & 7) * 256;
  const int kh = (local >> 3) & 1;
  const int bn = (local & 7) * 256;
  const int cnt = counts[e];
  if (bm >= cnt) return;
  const int base = offsets[e];
  const int Kh = K >> 1;
  unsigned short* __restrict__ C = kh ? C1 : C0;
  __shared__ unsigned short As[2][256 * 64];
  __shared__ unsigned short Bs[2][256 * 64];
  __shared__ int rowmap[256];
  const int tid = threadIdx.x, lane = tid & 63, wid = tid >> 6;
  const int wr = wid >> 2, wc = wid & 3;
  const int l16 = lane & 15, g4 = lane >> 4;
  const int rseg = lane >> 3;
  const int csw  = ((lane & 7) ^ rseg) * 8;
  if (tid < 256) {
    int lr = bm + tid;
    rowmap[tid] = (lr < cnt) ? (gather ? pair_token[base + lr] : base + lr) : -1;
  }
  __syncthreads();
  const unsigned short* BT = BTall + (size_t)e * N * K;
  const unsigned short* aSrc[4];
  const unsigned short* bSrc[4];
  int aOk[4];
  #pragma unroll
  for (int p = 0; p < 4; ++p) {
    int row = (p * 8 + wid) * 8 + rseg;
    int tok = rowmap[row];
    aOk[p] = (tok >= 0);
    aSrc[p] = aOk[p] ? (A + (size_t)tok * K + kh * Kh + csw) : (zbuf + csw);
    bSrc[p] = BT + (size_t)(bn + row) * K + kh * Kh + csw;
  }
  f32x4 acc[8][4] = {};
  const int NT = Kh >> 6;
  #pragma unroll
  for (int p = 0; p < 4; ++p) glds16(aSrc[p], &As[0][(p * 8 + wid) * 512]);
  #pragma unroll
  for (int p = 0; p < 4; ++p) glds16(bSrc[p], &Bs[0][(p * 8 + wid) * 512]);
  for (int t = 0; t < NT; ++t) {
    const int cur = t & 1;
    if (t + 1 < NT) {
      const int k0 = (t + 1) << 6;
      #pragma unroll
      for (int p = 0; p < 4; ++p)
        glds16(aSrc[p] + (aOk[p] ? k0 : 0), &As[cur ^ 1][(p * 8 + wid) * 512]);
      #pragma unroll
      for (int p = 0; p < 4; ++p)
        glds16(bSrc[p] + k0, &Bs[cur ^ 1][(p * 8 + wid) * 512]);
      asm volatile("s_waitcnt vmcnt(8)" ::: "memory");
    } else {
      asm volatile("s_waitcnt vmcnt(0)" ::: "memory");
    }
    __builtin_amdgcn_s_barrier();
    __builtin_amdgcn_sched_barrier(0);
    const unsigned short* ab = &As[cur][0];
    const unsigned short* bb = &Bs[cur][0];
    #pragma unroll
    for (int ks = 0; ks < 2; ++ks) {
      const int ch = ((ks * 4 + g4) ^ (l16 & 7)) * 8;
      bf16x8 bf[4];
      #pragma unroll
      for (int j = 0; j < 4; ++j)
        bf[j] = *(const bf16x8*)&bb[(wc * 64 + j * 16 + l16) * 64 + ch];
      #pragma unroll
      for (int mi = 0; mi < 8; ++mi) {
        bf16x8 af = *(const bf16x8*)&ab[(wr * 128 + mi * 16 + l16) * 64 + ch];
        #pragma unroll
        for (int ni = 0; ni < 4; ++ni)
          acc[mi][ni] = __builtin_amdgcn_mfma_f32_16x16x32_bf16(af, bf[ni], acc[mi][ni], 0, 0, 0);
      }
    }
    __builtin_amdgcn_sched_barrier(0);
    __builtin_amdgcn_s_barrier();
  }
  const int r4 = g4 * 4;
  #pragma unroll
  for (int mi = 0; mi < 8; ++mi)
    #pragma unroll
    for (int ni = 0; ni < 4; ++ni)
      #pragma unroll
      for (int r = 0; r < 4; ++r) {
        int lrow = bm + wr * 128 + mi * 16 + r4 + r;
        int col  = bn + wc * 64 + ni * 16 + l16;
        if (lrow < cnt)
          C[(size_t)(base + lrow) * N + col] = f2bf(acc[mi][ni][r]);
      }
}

// ---------------------------------------------------------------------------
// pre_norm: rows 0..2047 rmsnorm(hidden)->x_bf; rows 2048..3071 convert enc.
// ---------------------------------------------------------------------------
__global__ __launch_bounds__(256) void pre_norm(
    const float* __restrict__ hidden, const float* __restrict__ w,
    unsigned short* __restrict__ x_bf,
    const float* __restrict__ enc, unsigned short* __restrict__ enc_bf)
{
  const int row = blockIdx.x;
  const int tid = threadIdx.x;
  if (row >= 2048) {
    const int r = row - 2048;
    const float* x = enc + (size_t)r * 2048 + tid * 8;
    unsigned short* o = enc_bf + (size_t)r * 2048 + tid * 8;
    float4 a = *(const float4*)&x[0];
    float4 b = *(const float4*)&x[4];
    o[0] = f2bf(a.x); o[1] = f2bf(a.y); o[2] = f2bf(a.z); o[3] = f2bf(a.w);
    o[4] = f2bf(b.x); o[5] = f2bf(b.y); o[6] = f2bf(b.z); o[7] = f2bf(b.w);
    return;
  }
  const float* x = hidden + (size_t)row * 2048;
  float4 a = *(const float4*)&x[tid * 8];
  float4 b = *(const float4*)&x[tid * 8 + 4];
  float s = a.x*a.x + a.y*a.y + a.z*a.z + a.w*a.w
          + b.x*b.x + b.y*b.y + b.z*b.z + b.w*b.w;
  #pragma unroll
  for (int off = 1; off < 64; off <<= 1) s += __shfl_xor(s, off);
  __shared__ float red[4];
  if ((tid & 63) == 0) red[tid >> 6] = s;
  __syncthreads();
  float inv = rsqrtf((red[0] + red[1] + red[2] + red[3]) * (1.f / 2048.f) + 1e-6f);
  float4 wa = *(const float4*)&w[tid * 8];
  float4 wb = *(const float4*)&w[tid * 8 + 4];
  unsigned short* o = x_bf + (size_t)row * 2048 + tid * 8;
  o[0] = f2bf(a.x * inv * wa.x); o[1] = f2bf(a.y * inv * wa.y);
  o[2] = f2bf(a.z * inv * wa.z); o[3] = f2bf(a.w * inv * wa.w);
  o[4] = f2bf(b.x * inv * wb.x); o[5] = f2bf(b.y * inv * wb.y);
  o[6] = f2bf(b.z * inv * wb.z); o[7] = f2bf(b.w * inv * wb.w);
}

// ---------------------------------------------------------------------------
// Fused RMSNorm(norm2) + router.
// ---------------------------------------------------------------------------
__global__ __launch_bounds__(256) void rmsnorm_router(
    const float* __restrict__ in, const float* __restrict__ w,
    unsigned short* __restrict__ xt, const float* __restrict__ rw,
    int* __restrict__ topi, float* __restrict__ topw, int* __restrict__ counts)
{
  const int row = blockIdx.x;
  const int tid = threadIdx.x, lane = tid & 63, wid = tid >> 6;
  const float* x = in + (size_t)row * 2048;
  float4 a = *(const float4*)&x[tid * 8];
  float4 b = *(const float4*)&x[tid * 8 + 4];
  float s = a.x*a.x + a.y*a.y + a.z*a.z + a.w*a.w
          + b.x*b.x + b.y*b.y + b.z*b.z + b.w*b.w;
  #pragma unroll
  for (int off = 1; off < 64; off <<= 1) s += __shfl_xor(s, off);
  __shared__ float red[4];
  __shared__ float rl[4][8];
  if (lane == 0) red[wid] = s;
  __syncthreads();
  float inv = rsqrtf((red[0] + red[1] + red[2] + red[3]) * (1.f / 2048.f) + 1e-6f);
  float4 wa = *(const float4*)&w[tid * 8];
  float4 wb = *(const float4*)&w[tid * 8 + 4];
  float y[8] = {a.x * inv * wa.x, a.y * inv * wa.y, a.z * inv * wa.z, a.w * inv * wa.w,
                b.x * inv * wb.x, b.y * inv * wb.y, b.z * inv * wb.z, b.w * inv * wb.w};
  unsigned short* o = xt + (size_t)row * 2048 + tid * 8;
  #pragma unroll
  for (int j = 0; j < 8; ++j) o[j] = f2bf(y[j]);
  float lg[8] = {};
  #pragma unroll
  for (int j = 0; j < 8; ++j) {
    int d = tid * 8 + j;
    const float4 r0 = *(const float4*)&rw[d * 8];
    const float4 r1 = *(const float4*)&rw[d * 8 + 4];
    lg[0] += y[j] * r0.x; lg[1] += y[j] * r0.y; lg[2] += y[j] * r0.z; lg[3] += y[j] * r0.w;
    lg[4] += y[j] * r1.x; lg[5] += y[j] * r1.y; lg[6] += y[j] * r1.z; lg[7] += y[j] * r1.w;
  }
  #pragma unroll
  for (int e = 0; e < 8; ++e)
    #pragma unroll
    for (int off = 1; off < 64; off <<= 1) lg[e] += __shfl_xor(lg[e], off);
  if (lane == 0) {
    #pragma unroll
    for (int e = 0; e < 8; ++e) rl[wid][e] = lg[e];
  }
  __syncthreads();
  if (tid == 0) {
    float l[8];
    #pragma unroll
    for (int e = 0; e < 8; ++e) l[e] = rl[0][e] + rl[1][e] + rl[2][e] + rl[3][e];
    float v0 = l[0]; int e0 = 0;
    #pragma unroll
    for (int e = 1; e < 8; ++e) if (l[e] > v0) { v0 = l[e]; e0 = e; }
    float v1 = -1e30f; int e1 = 0;
    #pragma unroll
    for (int e = 0; e < 8; ++e) if (e != e0 && l[e] > v1) { v1 = l[e]; e1 = e; }
    float x1 = expf(v1 - v0);
    float w0 = 1.f / (1.f + x1);
    float w1 = x1 / (1.f + x1);
    topi[2 * row] = e0; topi[2 * row + 1] = e1;
    topw[2 * row] = w0; topw[2 * row + 1] = w1;
    atomicAdd(&counts[e0], 1);
    atomicAdd(&counts[e1], 1);
  }
}

// ---------------------------------------------------------------------------
// route_build: single block; scan + scatter via LDS atomics.
// ---------------------------------------------------------------------------
__global__ __launch_bounds__(256) void route_build(
    const int* __restrict__ counts, int* __restrict__ offsets,
    const int* __restrict__ topi,
    int* __restrict__ pair_token, int* __restrict__ token_slot)
{
  __shared__ int soff[9];
  __shared__ int sfill[8];
  const int tid = threadIdx.x;
  if (tid == 0) {
    int a = 0;
    #pragma unroll
    for (int e = 0; e < 8; ++e) { soff[e] = a; a += counts[e]; }
    soff[8] = a;
  }
  if (tid < 8) sfill[tid] = 0;
  __syncthreads();
  if (tid < 9) offsets[tid] = soff[tid];
  for (int t = tid; t < 2048; t += 256) {
    #pragma unroll
    for (int k = 0; k < 2; ++k) {
      int e = topi[2 * t + k];
      int slot = soff[e] + atomicAdd(&sfill[e], 1);
      pair_token[slot] = t;
      token_slot[2 * t + k] = slot;
    }
  }
}

// ---------------------------------------------------------------------------
// Merged attention + MoE/wo weight conversion. Blocks 0..255: attention
// (unchanged r12 body, xcd_swz over 256). Blocks 256+: convert v1 body at
// 512 threads for wo/gate_up/down. Shared LDS carved from one 48KB pool.
// ---------------------------------------------------------------------------
__global__ __launch_bounds__(512) void attn_plus_convert(
    const unsigned short* __restrict__ q,
    const unsigned short* __restrict__ kbuf,
    const unsigned short* __restrict__ vbuf,
    unsigned short* __restrict__ o,
    CvtJobs jb)
{
  __shared__ unsigned short SMEM[24576];   // 48 KB pool
  const int tid = threadIdx.x;

  if (blockIdx.x >= 256) {
    // ---------------- convert body (v1, 512 threads) ----------------
    unsigned short (*T)[66] = (unsigned short(*)[66])SMEM;
    const int bid = blockIdx.x - 256;
    int j = 0;
    #pragma unroll
    for (int i = 0; i < 8; ++i) if (bid >= jb.off[i + 1]) j = i + 1;
    const int local = bid - jb.off[j];
    const int K = jb.K[j], N = jb.N[j];
    const int kb2 = K >> 6, nb = N >> 6;
    const int kt = local % kb2;
    const int rest = local / kb2;
    const int nt = rest % nb, zi = rest / nb;
    const float* Wz = jb.src[j] + (size_t)zi * K * N;
    unsigned short* WTz = jb.dst[j] + (size_t)zi * K * N;
    const int k0 = kt * 64, n0 = nt * 64;
    #pragma unroll
    for (int i = tid; i < 64 * 16; i += 512) {
      int k = i >> 4, n4 = (i & 15) * 4;
      float4 v = *(const float4*)&Wz[(size_t)(k0 + k) * N + n0 + n4];
      T[n4 + 0][k] = f2bf(v.x);
      T[n4 + 1][k] = f2bf(v.y);
      T[n4 + 2][k] = f2bf(v.z);
      T[n4 + 3][k] = f2bf(v.w);
    }
    __syncthreads();
    {
      int i = tid;              // 512 elements, one per thread
      int n = i >> 3, k8 = (i & 7) * 8;
      *(u16x8*)&WTz[(size_t)(n0 + n) * K + k0 + k8] = *(const u16x8*)&T[n][k8];
    }
    return;
  }

  // ---------------- attention body (r12, unchanged) ----------------
  unsigned short* KsL = SMEM;            // 64*128
  unsigned short* VTL = SMEM + 8192;     // 128*64
  unsigned short* PsL = SMEM + 16384;    // 8*16*64
  const int SK = 1536;
  const int w = xcd_swz(blockIdx.x, 256);
  const int bh = w >> 3;
  const int b = bh >> 4, h = bh & 15, kvh = h >> 2;
  const int q0 = (w & 7) * 128;
  const int lane = tid & 63, wid = tid >> 6;
  const int l16 = lane & 15, kb = (lane >> 4) * 8, r4 = (lane >> 4) * 4;
  const int sr0 = tid >> 4;
  const int scc = (tid & 15) * 8;

  const unsigned short* qrow =
      q + ((size_t)(b * 16 + h) * 1024 + q0 + wid * 16 + l16) * 128;
  bf16x8 qf[4];
  #pragma unroll
  for (int ks = 0; ks < 4; ++ks) qf[ks] = *(const bf16x8*)&qrow[ks * 32 + kb];
  float mrow[4] = {-1e30f, -1e30f, -1e30f, -1e30f};
  float lrow[4] = {0.f, 0.f, 0.f, 0.f};
  f32x4 oacc[8] = {};
  const unsigned short* kb_base = kbuf + (size_t)(b * 4 + kvh) * SK * 128;
  const unsigned short* vb_base = vbuf + (size_t)(b * 4 + kvh) * SK * 128;

  u16x8 k0[2], v0[2], k1[2], v1[2];

#define ATT_LOAD(kr, vr, kt1)                                                 \
  {                                                                           \
    _Pragma("unroll")                                                         \
    for (int i = 0; i < 2; ++i) {                                             \
      kr[i] = *(const u16x8*)&kb_base[(size_t)((kt1) + sr0 + 32 * i) * 128 + scc]; \
      vr[i] = *(const u16x8*)&vb_base[(size_t)((kt1) + sr0 + 32 * i) * 128 + scc]; \
    }                                                                         \
  }

#define ATT_STAGE(kr, vr)                                                     \
  {                                                                           \
    _Pragma("unroll")                                                         \
    for (int i = 0; i < 2; ++i) {                                             \
      int rr = sr0 + 32 * i;                                                  \
      *(u16x8*)&KsL[rr * 128 + (((scc >> 3) ^ (rr & 7)) << 3)] = kr[i];       \
      _Pragma("unroll")                                                       \
      for (int jj = 0; jj < 8; ++jj)                                          \
        VTL[(scc + jj) * 64 + ((((rr >> 3) ^ ((scc + jj) >> 3)) & 7) << 3) + (rr & 7)] = vr[i][jj]; \
    }                                                                         \
  }

  auto compute = [&]() {
    f32x4 sacc[4] = {};
    __builtin_amdgcn_s_setprio(1);
    #pragma unroll
    for (int ks = 0; ks < 4; ++ks) {
      #pragma unroll
      for (int ni = 0; ni < 4; ++ni) {
        int rr = ni * 16 + l16;
        bf16x8 kf = *(const bf16x8*)
            &KsL[rr * 128 + ((((ks * 32 + kb) >> 3) ^ (rr & 7)) << 3)];
        sacc[ni] = __builtin_amdgcn_mfma_f32_16x16x32_bf16(qf[ks], kf, sacc[ni], 0, 0, 0);
      }
    }
    __builtin_amdgcn_s_setprio(0);
    float pv[4][4], alpha[4];
    #pragma unroll
    for (int r = 0; r < 4; ++r) {
      float tm = fmaxf(fmaxf(sacc[0][r], sacc[1][r]), fmaxf(sacc[2][r], sacc[3][r]));
      #pragma unroll
      for (int off = 1; off < 16; off <<= 1) tm = fmaxf(tm, __shfl_xor(tm, off));
      float mn = fmaxf(mrow[r], tm);
      alpha[r] = __expf(mrow[r] - mn);
      float s = 0.f;
      #pragma unroll
      for (int ni = 0; ni < 4; ++ni) {
        float p = __expf(sacc[ni][r] - mn);
        pv[ni][r] = p; s += p;
      }
      #pragma unroll
      for (int off = 1; off < 16; off <<= 1) s += __shfl_xor(s, off);
      lrow[r] = lrow[r] * alpha[r] + s;
      mrow[r] = mn;
    }
    #pragma unroll
    for (int ni = 0; ni < 8; ++ni)
      #pragma unroll
      for (int r = 0; r < 4; ++r) oacc[ni][r] *= alpha[r];
    #pragma unroll
    for (int ni = 0; ni < 4; ++ni)
      #pragma unroll
      for (int r = 0; r < 4; ++r) {
        int row = r4 + r, col = ni * 16 + l16;
        PsL[wid * 1024 + row * 64 + ((((col >> 3) ^ (row & 7)) & 7) << 3) + (col & 7)]
            = f2bf(pv[ni][r]);
      }
    asm volatile("s_waitcnt lgkmcnt(0)" ::: "memory");
    __builtin_amdgcn_sched_barrier(0);
    __builtin_amdgcn_s_setprio(1);
    #pragma unroll
    for (int ks = 0; ks < 2; ++ks) {
      bf16x8 pf = *(const bf16x8*)
          &PsL[wid * 1024 + l16 * 64 + ((((ks * 32 + kb) >> 3) ^ (l16 & 7)) << 3)];
      #pragma unroll
      for (int ni = 0; ni < 8; ++ni) {
        int d = ni * 16 + l16;
        bf16x8 vf = *(const bf16x8*)
            &VTL[d * 64 + ((((ks * 32 + kb) >> 3) ^ ((d >> 3) & 7)) << 3)];
        oacc[ni] = __builtin_amdgcn_mfma_f32_16x16x32_bf16(pf, vf, oacc[ni], 0, 0, 0);
      }
    }
    __builtin_amdgcn_s_setprio(0);
  };

  ATT_LOAD(k0, v0, 0);
  for (int t = 0; t < 24; t += 2) {
    ATT_STAGE(k0, v0);
    ATT_LOAD(k1, v1, (t + 1) * 64);
    asm volatile("s_waitcnt lgkmcnt(0)" ::: "memory");
    __builtin_amdgcn_s_barrier();
    __builtin_amdgcn_sched_barrier(0);
    compute();
    __builtin_amdgcn_sched_barrier(0);
    __builtin_amdgcn_s_barrier();
    ATT_STAGE(k1, v1);
    if (t + 2 < 24) ATT_LOAD(k0, v0, (t + 2) * 64);
    asm volatile("s_waitcnt lgkmcnt(0)" ::: "memory");
    __builtin_amdgcn_s_barrier();
    __builtin_amdgcn_sched_barrier(0);
    compute();
    __builtin_amdgcn_sched_barrier(0);
    __builtin_amdgcn_s_barrier();
  }
#undef ATT_LOAD
#undef ATT_STAGE

  #pragma unroll
  for (int ni = 0; ni < 8; ++ni)
    #pragma unroll
    for (int r = 0; r < 4; ++r) {
      float val = oacc[ni][r] / lrow[r];
      size_t row = (size_t)b * 1024 + q0 + wid * 16 + r4 + r;
      o[row * 2048 + h * 128 + ni * 16 + l16] = f2bf(val);
    }
}

// act_silu over summed bf16 split-K partials.
__global__ __launch_bounds__(256) void act_silu2(
    const unsigned short* __restrict__ gu0, const unsigned short* __restrict__ gu1,
    unsigned short* __restrict__ act)
{
  int p = blockIdx.x;
  int c = threadIdx.x * 4;
  u16x4 g0 = *(const u16x4*)&gu0[(size_t)p * 2048 + c];
  u16x4 g1 = *(const u16x4*)&gu1[(size_t)p * 2048 + c];
  u16x4 u0 = *(const u16x4*)&gu0[(size_t)p * 2048 + 1024 + c];
  u16x4 u1 = *(const u16x4*)&gu1[(size_t)p * 2048 + 1024 + c];
  #pragma unroll
  for (int j = 0; j < 4; ++j) {
    float g = bf2f(g0[j]) + bf2f(g1[j]);
    float u = bf2f(u0[j]) + bf2f(u1[j]);
    float a = g / (1.f + __expf(-g)) * u;
    act[(size_t)p * 1024 + c + j] = f2bf(a);
  }
}

// combine over summed bf16 split-K partials.
__global__ __launch_bounds__(256) void moe_combine2(
    float* __restrict__ out, const unsigned short* __restrict__ eo0,
    const unsigned short* __restrict__ eo1,
    const int* __restrict__ token_slot, const float* __restrict__ topw)
{
  int t = blockIdx.x;
  int c = threadIdx.x * 8;
  int s0 = token_slot[2 * t], s1 = token_slot[2 * t + 1];
  float w0 = topw[2 * t], w1 = topw[2 * t + 1];
  u16x8 a0 = *(const u16x8*)&eo0[(size_t)s0 * 2048 + c];
  u16x8 a1 = *(const u16x8*)&eo1[(size_t)s0 * 2048 + c];
  u16x8 b0 = *(const u16x8*)&eo0[(size_t)s1 * 2048 + c];
  u16x8 b1 = *(const u16x8*)&eo1[(size_t)s1 * 2048 + c];
  #pragma unroll
  for (int j0 = 0; j0 < 8; j0 += 4) {
    float4 v = *(const float4*)&out[(size_t)t * 2048 + c + j0];
    v.x += w0 * (bf2f(a0[j0+0]) + bf2f(a1[j0+0])) + w1 * (bf2f(b0[j0+0]) + bf2f(b1[j0+0]));
    v.y += w0 * (bf2f(a0[j0+1]) + bf2f(a1[j0+1])) + w1 * (bf2f(b0[j0+1]) + bf2f(b1[j0+1]));
    v.z += w0 * (bf2f(a0[j0+2]) + bf2f(a1[j0+2])) + w1 * (bf2f(b0[j0+2]) + bf2f(b1[j0+2]));
    v.w += w0 * (bf2f(a0[j0+3]) + bf2f(a1[j0+3])) + w1 * (bf2f(b0[j0+3]) + bf2f(b1[j0+3]));
    *(float4*)&out[(size_t)t * 2048 + c + j0] = v;
  }
}

// ---------------------------------------------------------------------------
extern "C" void kernel_launch(void* const* d_in, const int* in_sizes, int n_in,
                              void* d_out, int out_size, void* d_ws, size_t ws_size,
                              hipStream_t stream)
{
  const float* hidden  = (const float*)d_in[0];
  const float* enc     = (const float*)d_in[1];
  const float* img_cos = (const float*)d_in[2];
  const float* img_sin = (const float*)d_in[3];
  const float* txt_cos = (const float*)d_in[4];
  const float* txt_sin = (const float*)d_in[5];
  const float* norm1_w = (const float*)d_in[6];
  const float* norm2_w = (const float*)d_in[7];
  const float* wq      = (const float*)d_in[8];
  const float* wk      = (const float*)d_in[9];
  const float* wv      = (const float*)d_in[10];
  const float* wk_txt  = (const float*)d_in[11];
  const float* wv_txt  = (const float*)d_in[12];
  const float* wo      = (const float*)d_in[13];
  const float* q_norm_w       = (const float*)d_in[14];
  const float* k_norm_w       = (const float*)d_in[15];
  const float* added_k_norm_w = (const float*)d_in[16];
  const float* router_w       = (const float*)d_in[17];
  const float* gate_up_proj   = (const float*)d_in[18];
  const float* down_proj      = (const float*)d_in[19];
  float* out = (float*)d_out;

  char* ws = (char*)d_ws;
  size_t off = 0;
  auto alloc = [&](size_t bytes) {
    void* p = ws + off;
    off += (bytes + 255) & ~(size_t)255;
    return p;
  };
  unsigned short* wqkvT  = (unsigned short*)alloc(3072ULL * 2048 * 2);
  unsigned short* wkvtT  = (unsigned short*)alloc(1024ULL * 2048 * 2);
  unsigned short* woT    = (unsigned short*)alloc(2048ULL * 2048 * 2);
  unsigned short* gupT   = (unsigned short*)alloc(8ULL * 2048 * 2048 * 2);
  unsigned short* dnT    = (unsigned short*)alloc(8ULL * 2048 * 1024 * 2);
  unsigned short* x_bf   = (unsigned short*)alloc(2048ULL * 2048 * 2);
  unsigned short* enc_bf = (unsigned short*)alloc(1024ULL * 2048 * 2);
  unsigned short* gu0 = (unsigned short*)alloc(4096ULL * 2048 * 2);
  unsigned short* gu1 = (unsigned short*)alloc(4096ULL * 2048 * 2);
  unsigned short* qb   = (unsigned short*)alloc(2048ULL * 2048 * 2);
  unsigned short* kbuf = (unsigned short*)alloc(2ULL * 4 * 1536 * 128 * 2);
  unsigned short* vbuf = (unsigned short*)alloc(2ULL * 4 * 1536 * 128 * 2);
  unsigned short* obuf = (unsigned short*)alloc(2048ULL * 2048 * 2);
  unsigned short* act  = obuf;
  unsigned short* xt   = (unsigned short*)alloc(2048ULL * 2048 * 2);
  int*   ctrl  = (int*)alloc(64 * sizeof(int));
  int*   topi  = (int*)alloc(4096 * 4);
  float* topw  = (float*)alloc(4096 * 4);
  int*   tslot = (int*)alloc(4096 * 4);
  int*   ptok  = (int*)alloc(4096 * 4);
  unsigned short* zbuf = (unsigned short*)alloc(256);
  int* counts = ctrl, * offsets = ctrl + 16;

  hipMemsetAsync(ctrl, 0, 64, stream);
  hipMemsetAsync(zbuf, 0, 256, stream);

  const float scale = 0.08838834764831845f;  // 1/sqrt(128)

  // up-front convert: qkv + kvt weights only (needed by the first GEMMs)
  CvtJobs jb1;
  jb1.src[0] = wq;     jb1.dst[0] = wqkvT;                  jb1.K[0] = 2048; jb1.N[0] = 2048;
  jb1.src[1] = wk;     jb1.dst[1] = wqkvT + 2048ULL * 2048; jb1.K[1] = 2048; jb1.N[1] = 512;
  jb1.src[2] = wv;     jb1.dst[2] = wqkvT + 2560ULL * 2048; jb1.K[2] = 2048; jb1.N[2] = 512;
  jb1.src[3] = wk_txt; jb1.dst[3] = wkvtT;                  jb1.K[3] = 2048; jb1.N[3] = 512;
  jb1.src[4] = wv_txt; jb1.dst[4] = wkvtT + 512ULL * 2048;  jb1.K[4] = 2048; jb1.N[4] = 512;
  jb1.src[5] = wv_txt; jb1.dst[5] = wkvtT + 512ULL * 2048;  jb1.K[5] = 2048; jb1.N[5] = 512;
  jb1.src[6] = jb1.src[5]; jb1.dst[6] = jb1.dst[5]; jb1.K[6] = 2048; jb1.N[6] = 512;
  jb1.src[7] = jb1.src[5]; jb1.dst[7] = jb1.dst[5]; jb1.K[7] = 2048; jb1.N[7] = 512;
  // tiles: 1024, 256, 256, 256, 256 -> 2048
  jb1.off[0] = 0;    jb1.off[1] = 1024; jb1.off[2] = 1280; jb1.off[3] = 1536;
  jb1.off[4] = 1792; jb1.off[5] = 2048; jb1.off[6] = 2048; jb1.off[7] = 2048;
  jb1.off[8] = 2048;
  convert_small<<<2048, 256, 0, stream>>>(jb1);

  pre_norm<<<3072, 256, 0, stream>>>(hidden, norm1_w, x_bf, enc, enc_bf);

  Epi ep;
  ep.qb = qb; ep.kbuf = kbuf; ep.vbuf = vbuf;
  ep.q_nw = q_norm_w; ep.k_nw = k_norm_w; ep.kt_nw = added_k_norm_w;
  ep.icos = img_cos; ep.isin = img_sin; ep.tcos = txt_cos; ep.tsin = txt_sin;
  ep.scale = scale;

  gemm_bb<<<384, 256, 0, stream>>>(x_bf, wqkvT, nullptr, nullptr, 2048, 3072, 2048, 1, ep);
  gemm_bb<<<64, 256, 0, stream>>>(enc_bf, wkvtT, nullptr, nullptr, 1024, 1024, 2048, 2, ep);

  // attention + wo/gate_up/down conversion in one heterogeneous launch
  CvtJobs jb2;
  jb2.src[0] = wo;           jb2.dst[0] = woT;  jb2.K[0] = 2048; jb2.N[0] = 2048;
  jb2.src[1] = gate_up_proj; jb2.dst[1] = gupT; jb2.K[1] = 2048; jb2.N[1] = 2048;
  jb2.src[2] = down_proj;    jb2.dst[2] = dnT;  jb2.K[2] = 1024; jb2.N[2] = 2048;
  for (int i = 3; i < 8; ++i) { jb2.src[i] = wo; jb2.dst[i] = woT; jb2.K[i] = 2048; jb2.N[i] = 2048; }
  // tiles: wo 32*32=1024; gup 32*32*8=8192; dn 16*32*8=4096 -> 13312
  jb2.off[0] = 0;     jb2.off[1] = 1024;  jb2.off[2] = 9216;  jb2.off[3] = 13312;
  jb2.off[4] = 13312; jb2.off[5] = 13312; jb2.off[6] = 13312; jb2.off[7] = 13312;
  jb2.off[8] = 13312;
  attn_plus_convert<<<256 + 13312, 512, 0, stream>>>(qb, kbuf, vbuf, obuf, jb2);

  gemm_bb<<<256, 256, 0, stream>>>(obuf, woT, out, hidden, 2048, 2048, 2048, 0, ep);

  rmsnorm_router<<<2048, 256, 0, stream>>>(out, norm2_w, xt, router_w,
                                           topi, topw, counts);
  route_build<<<1, 256, 0, stream>>>(counts, offsets, topi, ptok, tslot);

  gemm_moe_256sk<<<1024, 512, 0, stream>>>(xt, gupT, gu0, gu1,
                                           counts, offsets, ptok, zbuf, 1, 2048, 2048);
  act_silu2<<<4096, 256, 0, stream>>>(gu0, gu1, act);
  gemm_moe_256sk<<<1024, 512, 0, stream>>>(act, dnT, gu0, gu1,
                                           counts, offsets, ptok, zbuf, 0, 1024, 2048);
  moe_combine2<<<2048, 256, 0, stream>>>(out, gu0, gu1, tslot, topw);
}

// Round 17
// 516.957 us; speedup vs baseline: 1.0997x; 1.0997x over previous
//
#include <hip/hip_runtime.h>

// ---------------------------------------------------------------------------
// NucleusMoEImageTransformerBlock round 17.
// B=2 SI=1024 ST=512 D=2048 H=16 KV=4 HD=128 E=8 F=1024 TOPK=2
// Round-17: REVERT r16's heterogeneous fusion (regressed 513->569: 48KB-LDS
// convert blocks capped at ~3/CU, throttling both attention and convert).
// Restore r14 (best: 513us) + T5 s_setprio around GEMM MFMA clusters
// (counted-vmcnt dbuf has wave role diversity at barriers -> m218b regime).
// ---------------------------------------------------------------------------

typedef __attribute__((ext_vector_type(8))) __bf16 bf16x8;
typedef __attribute__((ext_vector_type(8))) unsigned short u16x8;
typedef __attribute__((ext_vector_type(4))) unsigned short u16x4;
typedef __attribute__((ext_vector_type(4))) float f32x4;

__device__ __forceinline__ unsigned short f2bf(float x) {
  unsigned u = __builtin_bit_cast(unsigned, x);
  u += 0x7fffu + ((u >> 16) & 1u);        // RNE
  return (unsigned short)(u >> 16);
}
__device__ __forceinline__ float bf2f(unsigned short b) {
  return __builtin_bit_cast(float, ((unsigned)b) << 16);
}

__device__ __forceinline__ void glds16(const unsigned short* g, unsigned short* l) {
  __builtin_amdgcn_global_load_lds(
      (const __attribute__((address_space(1))) void*)g,
      (__attribute__((address_space(3))) void*)l, 16, 0, 0);
}

// m204 bijective XCD chunk swizzle.
__device__ __forceinline__ int xcd_swz(int orig, int nwg) {
  int q = nwg >> 3, r = nwg & 7;
  int xcd = orig & 7, idx = orig >> 3;
  int base = (xcd < r) ? xcd * (q + 1) : r * (q + 1) + (xcd - r) * q;
  return base + idx;
}

// ---------------------------------------------------------------------------
// Batched weight convert+transpose (v1, empirically best): f32 [K][N] ->
// bf16 [N][K], 64x64 tiles via [64][66] LDS.
// ---------------------------------------------------------------------------
struct CvtJobs {
  const float* src[8];
  unsigned short* dst[8];
  int K[8];
  int N[8];
  int off[9];
};

__global__ __launch_bounds__(256) void convert_all(CvtJobs jb)
{
  __shared__ unsigned short T[64][66];
  const int bid = blockIdx.x;
  int j = 0;
  #pragma unroll
  for (int i = 0; i < 8; ++i) if (bid >= jb.off[i + 1]) j = i + 1;
  const int local = bid - jb.off[j];
  const int K = jb.K[j], N = jb.N[j];
  const int kb = K >> 6, nb = N >> 6;
  const int kt = local % kb;
  const int rest = local / kb;
  const int nt = rest % nb, zi = rest / nb;
  const float* Wz = jb.src[j] + (size_t)zi * K * N;
  unsigned short* WTz = jb.dst[j] + (size_t)zi * K * N;
  const int k0 = kt * 64, n0 = nt * 64;
  const int tid = threadIdx.x;
  #pragma unroll
  for (int i = tid; i < 64 * 16; i += 256) {
    int k = i >> 4, n4 = (i & 15) * 4;
    float4 v = *(const float4*)&Wz[(size_t)(k0 + k) * N + n0 + n4];
    T[n4 + 0][k] = f2bf(v.x);
    T[n4 + 1][k] = f2bf(v.y);
    T[n4 + 2][k] = f2bf(v.z);
    T[n4 + 3][k] = f2bf(v.w);
  }
  __syncthreads();
  #pragma unroll
  for (int i = tid; i < 64 * 8; i += 256) {
    int n = i >> 3, k8 = (i & 7) * 8;
    *(u16x8*)&WTz[(size_t)(n0 + n) * K + k0 + k8] = *(const u16x8*)&T[n][k8];
  }
}

// ---------------------------------------------------------------------------
// Epilogue argument bundle for gemm_bb modes 1/2.
// ---------------------------------------------------------------------------
struct Epi {
  unsigned short* qb;
  unsigned short* kbuf;
  unsigned short* vbuf;
  const float* q_nw;
  const float* k_nw;
  const float* kt_nw;
  const float* icos;
  const float* isin;
  const float* tcos;
  const float* tsin;
  float scale;
};

// ---------------------------------------------------------------------------
// Dense GEMM (modes as r13): 128x128 tile, counted-vmcnt dbuf pipeline.
// ---------------------------------------------------------------------------
__global__ __launch_bounds__(256) void gemm_bb(
    const unsigned short* __restrict__ A, const unsigned short* __restrict__ BT,
    float* __restrict__ C, const float* __restrict__ resid,
    int M, int N, int K, int mode, Epi ep)
{
  __shared__ unsigned short As[2][128 * 64];
  __shared__ unsigned short Bs[2][128 * 64];
  const int mb = M >> 7;
  const int w = xcd_swz(blockIdx.x, gridDim.x);
  const int bm = (w % mb) * 128, bn = (w / mb) * 128;
  const int tid = threadIdx.x, lane = tid & 63, wid = tid >> 6;
  const int wm = (wid >> 1) * 64, wn = (wid & 1) * 64;
  const int l16 = lane & 15, g4 = lane >> 4;
  const int rseg = lane >> 3;
  const int csw  = ((lane & 7) ^ rseg) * 8;
  const unsigned short* aSrc[4];
  const unsigned short* bSrc[4];
  #pragma unroll
  for (int p = 0; p < 4; ++p) {
    int row = (p * 4 + wid) * 8 + rseg;
    aSrc[p] = A  + (size_t)(bm + row) * K + csw;
    bSrc[p] = BT + (size_t)(bn + row) * K + csw;
  }
  f32x4 acc[4][4] = {};
  const int NT = K >> 6;
  #pragma unroll
  for (int p = 0; p < 4; ++p) glds16(aSrc[p], &As[0][(p * 4 + wid) * 512]);
  #pragma unroll
  for (int p = 0; p < 4; ++p) glds16(bSrc[p], &Bs[0][(p * 4 + wid) * 512]);
  for (int t = 0; t < NT; ++t) {
    const int cur = t & 1;
    if (t + 1 < NT) {
      const int k0 = (t + 1) << 6;
      #pragma unroll
      for (int p = 0; p < 4; ++p) glds16(aSrc[p] + k0, &As[cur ^ 1][(p * 4 + wid) * 512]);
      #pragma unroll
      for (int p = 0; p < 4; ++p) glds16(bSrc[p] + k0, &Bs[cur ^ 1][(p * 4 + wid) * 512]);
      asm volatile("s_waitcnt vmcnt(8)" ::: "memory");
    } else {
      asm volatile("s_waitcnt vmcnt(0)" ::: "memory");
    }
    __builtin_amdgcn_s_barrier();
    __builtin_amdgcn_sched_barrier(0);
    const unsigned short* ab = &As[cur][0];
    const unsigned short* bb = &Bs[cur][0];
    __builtin_amdgcn_s_setprio(1);
    #pragma unroll
    for (int ks = 0; ks < 2; ++ks) {
      bf16x8 af[4], bf[4];
      #pragma unroll
      for (int i = 0; i < 4; ++i) {
        int ra = wm + i * 16 + l16;
        int rb = wn + i * 16 + l16;
        int ch = ((ks * 4 + g4) ^ (l16 & 7)) * 8;
        af[i] = *(const bf16x8*)&ab[ra * 64 + ch];
        bf[i] = *(const bf16x8*)&bb[rb * 64 + ch];
      }
      #pragma unroll
      for (int mi = 0; mi < 4; ++mi)
        #pragma unroll
        for (int ni = 0; ni < 4; ++ni)
          acc[mi][ni] = __builtin_amdgcn_mfma_f32_16x16x32_bf16(af[mi], bf[ni], acc[mi][ni], 0, 0, 0);
    }
    __builtin_amdgcn_s_setprio(0);
    __builtin_amdgcn_sched_barrier(0);
    __builtin_amdgcn_s_barrier();
  }
  const int r4 = g4 * 4;

  if (mode == 0) {
    #pragma unroll
    for (int mi = 0; mi < 4; ++mi)
      #pragma unroll
      for (int ni = 0; ni < 4; ++ni)
        #pragma unroll
        for (int r = 0; r < 4; ++r) {
          int row = bm + wm + mi * 16 + r4 + r;
          int col = bn + wn + ni * 16 + l16;
          float v = acc[mi][ni][r];
          if (resid) v += resid[(size_t)row * N + col];
          C[(size_t)row * N + col] = v;
        }
    return;
  }

  // ---- fused head-norm / rope / relayout epilogue (modes 1,2) ----
  const int bt = bn >> 7;
  unsigned short* dst;
  const float* nw = nullptr;
  const float* cosT = nullptr;
  const float* sinT = nullptr;
  int h, NH, st, soff, vkind = 0, shift;
  float premul = 1.f;
  int S;
  if (mode == 1) {
    S = 1024; shift = 10;
    if (bt < 16)      { h = bt;      dst = ep.qb;   nw = ep.q_nw; cosT = ep.icos; sinT = ep.isin;
                        NH = 16; st = 1024; soff = 0; premul = ep.scale; }
    else if (bt < 20) { h = bt - 16; dst = ep.kbuf; nw = ep.k_nw; cosT = ep.icos; sinT = ep.isin;
                        NH = 4;  st = 1536; soff = 0; }
    else              { h = bt - 20; dst = ep.vbuf; vkind = 1; NH = 4; st = 1536; soff = 0; }
  } else {
    S = 512; shift = 9;
    if (bt < 4) { h = bt;     dst = ep.kbuf; nw = ep.kt_nw; cosT = ep.tcos; sinT = ep.tsin;
                  NH = 4; st = 1536; soff = 1024; }
    else        { h = bt - 4; dst = ep.vbuf; vkind = 1; NH = 4; st = 1536; soff = 1024; }
  }

  if (vkind) {
    #pragma unroll
    for (int mi = 0; mi < 4; ++mi)
      #pragma unroll
      for (int ni = 0; ni < 4; ++ni)
        #pragma unroll
        for (int r = 0; r < 4; ++r) {
          int row = wm + mi * 16 + r4 + r;
          int d   = wn + ni * 16 + l16;
          int token = bm + row;
          int srow = token & (S - 1), bidx = token >> shift;
          dst[((size_t)(bidx * NH + h) * st + srow + soff) * 128 + d] = f2bf(acc[mi][ni][r]);
        }
    return;
  }

  float* ssb = (float*)&As[0][0];
  float ssp[4][4];
  #pragma unroll
  for (int mi = 0; mi < 4; ++mi)
    #pragma unroll
    for (int r = 0; r < 4; ++r) {
      float v = 0.f;
      #pragma unroll
      for (int ni = 0; ni < 4; ++ni) v += acc[mi][ni][r] * acc[mi][ni][r];
      #pragma unroll
      for (int off = 1; off < 16; off <<= 1) v += __shfl_xor(v, off);
      ssp[mi][r] = v;
    }
  __syncthreads();
  if (l16 == 0) {
    #pragma unroll
    for (int mi = 0; mi < 4; ++mi)
      #pragma unroll
      for (int r = 0; r < 4; ++r)
        ssb[(wid & 1) * 128 + wm + mi * 16 + r4 + r] = ssp[mi][r];
  }
  __syncthreads();
  #pragma unroll
  for (int mi = 0; mi < 4; ++mi)
    #pragma unroll
    for (int r = 0; r < 4; ++r) {
      int row = wm + mi * 16 + r4 + r;
      float tot = ssb[row] + ssb[128 + row];
      float inv = rsqrtf(tot * (1.f / 128.f) + 1e-6f);
      int token = bm + row;
      int srow = token & (S - 1), bidx = token >> shift;
      #pragma unroll
      for (int ni = 0; ni < 4; ++ni) {
        int d = wn + ni * 16 + l16;
        float y = acc[mi][ni][r] * inv * nw[d];
        float part = __shfl_xor(y, 1);
        float c  = cosT[srow * 64 + (d >> 1)];
        float sn = sinT[srow * 64 + (d >> 1)];
        float outv = (d & 1) ? (part * sn + y * c) : (y * c - part * sn);
        dst[((size_t)(bidx * NH + h) * st + srow + soff) * 128 + d] = f2bf(outv * premul);
      }
    }
}

// ---------------------------------------------------------------------------
// Expert-batched MoE GEMM, 256x256 tile, split-K=2, counted-vmcnt dbuf,
// bf16 partial outputs. Grid 1024 = 8bm x 2kh x 8bn x 8e, XCD-swizzled.
// ---------------------------------------------------------------------------
__global__ __launch_bounds__(512, 1) void gemm_moe_256sk(
    const unsigned short* __restrict__ A, const unsigned short* __restrict__ BTall,
    unsigned short* __restrict__ C0, unsigned short* __restrict__ C1,
    const int* __restrict__ counts, const int* __restrict__ offsets,
    const int* __restrict__ pair_token, const unsigned short* __restrict__ zbuf,
    int gather, int K, int N)
{
  const int w = xcd_swz(blockIdx.x, gridDim.x);
  const int e = w >> 7;
  const int local = w & 127;
  const int bm = ((local >> 4) & 7) * 256;
  const int kh = (local >> 3) & 1;
  const int bn = (local & 7) * 256;
  const int cnt = counts[e];
  if (bm >= cnt) return;
  const int base = offsets[e];
  const int Kh = K >> 1;
  unsigned short* __restrict__ C = kh ? C1 : C0;
  __shared__ unsigned short As[2][256 * 64];
  __shared__ unsigned short Bs[2][256 * 64];
  __shared__ int rowmap[256];
  const int tid = threadIdx.x, lane = tid & 63, wid = tid >> 6;
  const int wr = wid >> 2, wc = wid & 3;
  const int l16 = lane & 15, g4 = lane >> 4;
  const int rseg = lane >> 3;
  const int csw  = ((lane & 7) ^ rseg) * 8;
  if (tid < 256) {
    int lr = bm + tid;
    rowmap[tid] = (lr < cnt) ? (gather ? pair_token[base + lr] : base + lr) : -1;
  }
  __syncthreads();
  const unsigned short* BT = BTall + (size_t)e * N * K;
  const unsigned short* aSrc[4];
  const unsigned short* bSrc[4];
  int aOk[4];
  #pragma unroll
  for (int p = 0; p < 4; ++p) {
    int row = (p * 8 + wid) * 8 + rseg;
    int tok = rowmap[row];
    aOk[p] = (tok >= 0);
    aSrc[p] = aOk[p] ? (A + (size_t)tok * K + kh * Kh + csw) : (zbuf + csw);
    bSrc[p] = BT + (size_t)(bn + row) * K + kh * Kh + csw;
  }
  f32x4 acc[8][4] = {};
  const int NT = Kh >> 6;
  #pragma unroll
  for (int p = 0; p < 4; ++p) glds16(aSrc[p], &As[0][(p * 8 + wid) * 512]);
  #pragma unroll
  for (int p = 0; p < 4; ++p) glds16(bSrc[p], &Bs[0][(p * 8 + wid) * 512]);
  for (int t = 0; t < NT; ++t) {
    const int cur = t & 1;
    if (t + 1 < NT) {
      const int k0 = (t + 1) << 6;
      #pragma unroll
      for (int p = 0; p < 4; ++p)
        glds16(aSrc[p] + (aOk[p] ? k0 : 0), &As[cur ^ 1][(p * 8 + wid) * 512]);
      #pragma unroll
      for (int p = 0; p < 4; ++p)
        glds16(bSrc[p] + k0, &Bs[cur ^ 1][(p * 8 + wid) * 512]);
      asm volatile("s_waitcnt vmcnt(8)" ::: "memory");
    } else {
      asm volatile("s_waitcnt vmcnt(0)" ::: "memory");
    }
    __builtin_amdgcn_s_barrier();
    __builtin_amdgcn_sched_barrier(0);
    const unsigned short* ab = &As[cur][0];
    const unsigned short* bb = &Bs[cur][0];
    __builtin_amdgcn_s_setprio(1);
    #pragma unroll
    for (int ks = 0; ks < 2; ++ks) {
      const int ch = ((ks * 4 + g4) ^ (l16 & 7)) * 8;
      bf16x8 bf[4];
      #pragma unroll
      for (int j = 0; j < 4; ++j)
        bf[j] = *(const bf16x8*)&bb[(wc * 64 + j * 16 + l16) * 64 + ch];
      #pragma unroll
      for (int mi = 0; mi < 8; ++mi) {
        bf16x8 af = *(const bf16x8*)&ab[(wr * 128 + mi * 16 + l16) * 64 + ch];
        #pragma unroll
        for (int ni = 0; ni < 4; ++ni)
          acc[mi][ni] = __builtin_amdgcn_mfma_f32_16x16x32_bf16(af, bf[ni], acc[mi][ni], 0, 0, 0);
      }
    }
    __builtin_amdgcn_s_setprio(0);
    __builtin_amdgcn_sched_barrier(0);
    __builtin_amdgcn_s_barrier();
  }
  const int r4 = g4 * 4;
  #pragma unroll
  for (int mi = 0; mi < 8; ++mi)
    #pragma unroll
    for (int ni = 0; ni < 4; ++ni)
      #pragma unroll
      for (int r = 0; r < 4; ++r) {
        int lrow = bm + wr * 128 + mi * 16 + r4 + r;
        int col  = bn + wc * 64 + ni * 16 + l16;
        if (lrow < cnt)
          C[(size_t)(base + lrow) * N + col] = f2bf(acc[mi][ni][r]);
      }
}

// ---------------------------------------------------------------------------
// pre_norm: rows 0..2047 rmsnorm(hidden)->x_bf; rows 2048..3071 convert enc.
// ---------------------------------------------------------------------------
__global__ __launch_bounds__(256) void pre_norm(
    const float* __restrict__ hidden, const float* __restrict__ w,
    unsigned short* __restrict__ x_bf,
    const float* __restrict__ enc, unsigned short* __restrict__ enc_bf)
{
  const int row = blockIdx.x;
  const int tid = threadIdx.x;
  if (row >= 2048) {
    const int r = row - 2048;
    const float* x = enc + (size_t)r * 2048 + tid * 8;
    unsigned short* o = enc_bf + (size_t)r * 2048 + tid * 8;
    float4 a = *(const float4*)&x[0];
    float4 b = *(const float4*)&x[4];
    o[0] = f2bf(a.x); o[1] = f2bf(a.y); o[2] = f2bf(a.z); o[3] = f2bf(a.w);
    o[4] = f2bf(b.x); o[5] = f2bf(b.y); o[6] = f2bf(b.z); o[7] = f2bf(b.w);
    return;
  }
  const float* x = hidden + (size_t)row * 2048;
  float4 a = *(const float4*)&x[tid * 8];
  float4 b = *(const float4*)&x[tid * 8 + 4];
  float s = a.x*a.x + a.y*a.y + a.z*a.z + a.w*a.w
          + b.x*b.x + b.y*b.y + b.z*b.z + b.w*b.w;
  #pragma unroll
  for (int off = 1; off < 64; off <<= 1) s += __shfl_xor(s, off);
  __shared__ float red[4];
  if ((tid & 63) == 0) red[tid >> 6] = s;
  __syncthreads();
  float inv = rsqrtf((red[0] + red[1] + red[2] + red[3]) * (1.f / 2048.f) + 1e-6f);
  float4 wa = *(const float4*)&w[tid * 8];
  float4 wb = *(const float4*)&w[tid * 8 + 4];
  unsigned short* o = x_bf + (size_t)row * 2048 + tid * 8;
  o[0] = f2bf(a.x * inv * wa.x); o[1] = f2bf(a.y * inv * wa.y);
  o[2] = f2bf(a.z * inv * wa.z); o[3] = f2bf(a.w * inv * wa.w);
  o[4] = f2bf(b.x * inv * wb.x); o[5] = f2bf(b.y * inv * wb.y);
  o[6] = f2bf(b.z * inv * wb.z); o[7] = f2bf(b.w * inv * wb.w);
}

// ---------------------------------------------------------------------------
// Fused RMSNorm(norm2) + router: bf16 xt out + exact-f32 top-2 routing.
// ---------------------------------------------------------------------------
__global__ __launch_bounds__(256) void rmsnorm_router(
    const float* __restrict__ in, const float* __restrict__ w,
    unsigned short* __restrict__ xt, const float* __restrict__ rw,
    int* __restrict__ topi, float* __restrict__ topw, int* __restrict__ counts)
{
  const int row = blockIdx.x;
  const int tid = threadIdx.x, lane = tid & 63, wid = tid >> 6;
  const float* x = in + (size_t)row * 2048;
  float4 a = *(const float4*)&x[tid * 8];
  float4 b = *(const float4*)&x[tid * 8 + 4];
  float s = a.x*a.x + a.y*a.y + a.z*a.z + a.w*a.w
          + b.x*b.x + b.y*b.y + b.z*b.z + b.w*b.w;
  #pragma unroll
  for (int off = 1; off < 64; off <<= 1) s += __shfl_xor(s, off);
  __shared__ float red[4];
  __shared__ float rl[4][8];
  if (lane == 0) red[wid] = s;
  __syncthreads();
  float inv = rsqrtf((red[0] + red[1] + red[2] + red[3]) * (1.f / 2048.f) + 1e-6f);
  float4 wa = *(const float4*)&w[tid * 8];
  float4 wb = *(const float4*)&w[tid * 8 + 4];
  float y[8] = {a.x * inv * wa.x, a.y * inv * wa.y, a.z * inv * wa.z, a.w * inv * wa.w,
                b.x * inv * wb.x, b.y * inv * wb.y, b.z * inv * wb.z, b.w * inv * wb.w};
  unsigned short* o = xt + (size_t)row * 2048 + tid * 8;
  #pragma unroll
  for (int j = 0; j < 8; ++j) o[j] = f2bf(y[j]);
  float lg[8] = {};
  #pragma unroll
  for (int j = 0; j < 8; ++j) {
    int d = tid * 8 + j;
    const float4 r0 = *(const float4*)&rw[d * 8];
    const float4 r1 = *(const float4*)&rw[d * 8 + 4];
    lg[0] += y[j] * r0.x; lg[1] += y[j] * r0.y; lg[2] += y[j] * r0.z; lg[3] += y[j] * r0.w;
    lg[4] += y[j] * r1.x; lg[5] += y[j] * r1.y; lg[6] += y[j] * r1.z; lg[7] += y[j] * r1.w;
  }
  #pragma unroll
  for (int e = 0; e < 8; ++e)
    #pragma unroll
    for (int off = 1; off < 64; off <<= 1) lg[e] += __shfl_xor(lg[e], off);
  if (lane == 0) {
    #pragma unroll
    for (int e = 0; e < 8; ++e) rl[wid][e] = lg[e];
  }
  __syncthreads();
  if (tid == 0) {
    float l[8];
    #pragma unroll
    for (int e = 0; e < 8; ++e) l[e] = rl[0][e] + rl[1][e] + rl[2][e] + rl[3][e];
    float v0 = l[0]; int e0 = 0;
    #pragma unroll
    for (int e = 1; e < 8; ++e) if (l[e] > v0) { v0 = l[e]; e0 = e; }
    float v1 = -1e30f; int e1 = 0;
    #pragma unroll
    for (int e = 0; e < 8; ++e) if (e != e0 && l[e] > v1) { v1 = l[e]; e1 = e; }
    float x1 = expf(v1 - v0);
    float w0 = 1.f / (1.f + x1);
    float w1 = x1 / (1.f + x1);
    topi[2 * row] = e0; topi[2 * row + 1] = e1;
    topw[2 * row] = w0; topw[2 * row + 1] = w1;
    atomicAdd(&counts[e0], 1);
    atomicAdd(&counts[e1], 1);
  }
}

// ---------------------------------------------------------------------------
// route_build: single block. Scan counts -> offsets, scatter via LDS atomics.
// ---------------------------------------------------------------------------
__global__ __launch_bounds__(256) void route_build(
    const int* __restrict__ counts, int* __restrict__ offsets,
    const int* __restrict__ topi,
    int* __restrict__ pair_token, int* __restrict__ token_slot)
{
  __shared__ int soff[9];
  __shared__ int sfill[8];
  const int tid = threadIdx.x;
  if (tid == 0) {
    int a = 0;
    #pragma unroll
    for (int e = 0; e < 8; ++e) { soff[e] = a; a += counts[e]; }
    soff[8] = a;
  }
  if (tid < 8) sfill[tid] = 0;
  __syncthreads();
  if (tid < 9) offsets[tid] = soff[tid];
  for (int t = tid; t < 2048; t += 256) {
    #pragma unroll
    for (int k = 0; k < 2; ++k) {
      int e = topi[2 * t + k];
      int slot = soff[e] + atomicAdd(&sfill[e], 1);
      pair_token[slot] = t;
      token_slot[2 * t + k] = slot;
    }
  }
}

// ---------------------------------------------------------------------------
// Flash attention (r12 form): 128 q-rows/block, grid 256.
// ---------------------------------------------------------------------------
__global__ __launch_bounds__(512) void attn_kernel(
    const unsigned short* __restrict__ q,
    const unsigned short* __restrict__ kbuf,
    const unsigned short* __restrict__ vbuf,
    unsigned short* __restrict__ o)
{
  const int SK = 1536;
  const int w = xcd_swz(blockIdx.x, gridDim.x);
  const int bh = w >> 3;
  const int b = bh >> 4, h = bh & 15, kvh = h >> 2;
  const int q0 = (w & 7) * 128;
  const int tid = threadIdx.x, lane = tid & 63, wid = tid >> 6;
  const int l16 = lane & 15, kb = (lane >> 4) * 8, r4 = (lane >> 4) * 4;
  __shared__ unsigned short KsL[64 * 128];
  __shared__ unsigned short VTL[128 * 64];
  __shared__ unsigned short PsL[8 * 16 * 64];
  const int sr0 = tid >> 4;
  const int scc = (tid & 15) * 8;

  const unsigned short* qrow =
      q + ((size_t)(b * 16 + h) * 1024 + q0 + wid * 16 + l16) * 128;
  bf16x8 qf[4];
  #pragma unroll
  for (int ks = 0; ks < 4; ++ks) qf[ks] = *(const bf16x8*)&qrow[ks * 32 + kb];
  float mrow[4] = {-1e30f, -1e30f, -1e30f, -1e30f};
  float lrow[4] = {0.f, 0.f, 0.f, 0.f};
  f32x4 oacc[8] = {};
  const unsigned short* kb_base = kbuf + (size_t)(b * 4 + kvh) * SK * 128;
  const unsigned short* vb_base = vbuf + (size_t)(b * 4 + kvh) * SK * 128;

  u16x8 k0[2], v0[2], k1[2], v1[2];

#define ATT_LOAD(kr, vr, kt1)                                                 \
  {                                                                           \
    _Pragma("unroll")                                                         \
    for (int i = 0; i < 2; ++i) {                                             \
      kr[i] = *(const u16x8*)&kb_base[(size_t)((kt1) + sr0 + 32 * i) * 128 + scc]; \
      vr[i] = *(const u16x8*)&vb_base[(size_t)((kt1) + sr0 + 32 * i) * 128 + scc]; \
    }                                                                         \
  }

#define ATT_STAGE(kr, vr)                                                     \
  {                                                                           \
    _Pragma("unroll")                                                         \
    for (int i = 0; i < 2; ++i) {                                             \
      int rr = sr0 + 32 * i;                                                  \
      *(u16x8*)&KsL[rr * 128 + (((scc >> 3) ^ (rr & 7)) << 3)] = kr[i];       \
      _Pragma("unroll")                                                       \
      for (int j = 0; j < 8; ++j)                                             \
        VTL[(scc + j) * 64 + ((((rr >> 3) ^ ((scc + j) >> 3)) & 7) << 3) + (rr & 7)] = vr[i][j]; \
    }                                                                         \
  }

  auto compute = [&]() {
    f32x4 sacc[4] = {};
    __builtin_amdgcn_s_setprio(1);
    #pragma unroll
    for (int ks = 0; ks < 4; ++ks) {
      #pragma unroll
      for (int ni = 0; ni < 4; ++ni) {
        int rr = ni * 16 + l16;
        bf16x8 kf = *(const bf16x8*)
            &KsL[rr * 128 + ((((ks * 32 + kb) >> 3) ^ (rr & 7)) << 3)];
        sacc[ni] = __builtin_amdgcn_mfma_f32_16x16x32_bf16(qf[ks], kf, sacc[ni], 0, 0, 0);
      }
    }
    __builtin_amdgcn_s_setprio(0);
    float pv[4][4], alpha[4];
    #pragma unroll
    for (int r = 0; r < 4; ++r) {
      float tm = fmaxf(fmaxf(sacc[0][r], sacc[1][r]), fmaxf(sacc[2][r], sacc[3][r]));
      #pragma unroll
      for (int off = 1; off < 16; off <<= 1) tm = fmaxf(tm, __shfl_xor(tm, off));
      float mn = fmaxf(mrow[r], tm);
      alpha[r] = __expf(mrow[r] - mn);
      float s = 0.f;
      #pragma unroll
      for (int ni = 0; ni < 4; ++ni) {
        float p = __expf(sacc[ni][r] - mn);
        pv[ni][r] = p; s += p;
      }
      #pragma unroll
      for (int off = 1; off < 16; off <<= 1) s += __shfl_xor(s, off);
      lrow[r] = lrow[r] * alpha[r] + s;
      mrow[r] = mn;
    }
    #pragma unroll
    for (int ni = 0; ni < 8; ++ni)
      #pragma unroll
      for (int r = 0; r < 4; ++r) oacc[ni][r] *= alpha[r];
    #pragma unroll
    for (int ni = 0; ni < 4; ++ni)
      #pragma unroll
      for (int r = 0; r < 4; ++r) {
        int row = r4 + r, col = ni * 16 + l16;
        PsL[wid * 1024 + row * 64 + ((((col >> 3) ^ (row & 7)) & 7) << 3) + (col & 7)]
            = f2bf(pv[ni][r]);
      }
    asm volatile("s_waitcnt lgkmcnt(0)" ::: "memory");
    __builtin_amdgcn_sched_barrier(0);
    __builtin_amdgcn_s_setprio(1);
    #pragma unroll
    for (int ks = 0; ks < 2; ++ks) {
      bf16x8 pf = *(const bf16x8*)
          &PsL[wid * 1024 + l16 * 64 + ((((ks * 32 + kb) >> 3) ^ (l16 & 7)) << 3)];
      #pragma unroll
      for (int ni = 0; ni < 8; ++ni) {
        int d = ni * 16 + l16;
        bf16x8 vf = *(const bf16x8*)
            &VTL[d * 64 + ((((ks * 32 + kb) >> 3) ^ ((d >> 3) & 7)) << 3)];
        oacc[ni] = __builtin_amdgcn_mfma_f32_16x16x32_bf16(pf, vf, oacc[ni], 0, 0, 0);
      }
    }
    __builtin_amdgcn_s_setprio(0);
  };

  ATT_LOAD(k0, v0, 0);
  for (int t = 0; t < 24; t += 2) {
    ATT_STAGE(k0, v0);
    ATT_LOAD(k1, v1, (t + 1) * 64);
    asm volatile("s_waitcnt lgkmcnt(0)" ::: "memory");
    __builtin_amdgcn_s_barrier();
    __builtin_amdgcn_sched_barrier(0);
    compute();
    __builtin_amdgcn_sched_barrier(0);
    __builtin_amdgcn_s_barrier();
    ATT_STAGE(k1, v1);
    if (t + 2 < 24) ATT_LOAD(k0, v0, (t + 2) * 64);
    asm volatile("s_waitcnt lgkmcnt(0)" ::: "memory");
    __builtin_amdgcn_s_barrier();
    __builtin_amdgcn_sched_barrier(0);
    compute();
    __builtin_amdgcn_sched_barrier(0);
    __builtin_amdgcn_s_barrier();
  }
#undef ATT_LOAD
#undef ATT_STAGE

  #pragma unroll
  for (int ni = 0; ni < 8; ++ni)
    #pragma unroll
    for (int r = 0; r < 4; ++r) {
      float val = oacc[ni][r] / lrow[r];
      size_t row = (size_t)b * 1024 + q0 + wid * 16 + r4 + r;
      o[row * 2048 + h * 128 + ni * 16 + l16] = f2bf(val);
    }
}

// act_silu over summed bf16 split-K partials.
__global__ __launch_bounds__(256) void act_silu2(
    const unsigned short* __restrict__ gu0, const unsigned short* __restrict__ gu1,
    unsigned short* __restrict__ act)
{
  int p = blockIdx.x;
  int c = threadIdx.x * 4;
  u16x4 g0 = *(const u16x4*)&gu0[(size_t)p * 2048 + c];
  u16x4 g1 = *(const u16x4*)&gu1[(size_t)p * 2048 + c];
  u16x4 u0 = *(const u16x4*)&gu0[(size_t)p * 2048 + 1024 + c];
  u16x4 u1 = *(const u16x4*)&gu1[(size_t)p * 2048 + 1024 + c];
  #pragma unroll
  for (int j = 0; j < 4; ++j) {
    float g = bf2f(g0[j]) + bf2f(g1[j]);
    float u = bf2f(u0[j]) + bf2f(u1[j]);
    float a = g / (1.f + __expf(-g)) * u;
    act[(size_t)p * 1024 + c + j] = f2bf(a);
  }
}

// combine over summed bf16 split-K partials.
__global__ __launch_bounds__(256) void moe_combine2(
    float* __restrict__ out, const unsigned short* __restrict__ eo0,
    const unsigned short* __restrict__ eo1,
    const int* __restrict__ token_slot, const float* __restrict__ topw)
{
  int t = blockIdx.x;
  int c = threadIdx.x * 8;
  int s0 = token_slot[2 * t], s1 = token_slot[2 * t + 1];
  float w0 = topw[2 * t], w1 = topw[2 * t + 1];
  u16x8 a0 = *(const u16x8*)&eo0[(size_t)s0 * 2048 + c];
  u16x8 a1 = *(const u16x8*)&eo1[(size_t)s0 * 2048 + c];
  u16x8 b0 = *(const u16x8*)&eo0[(size_t)s1 * 2048 + c];
  u16x8 b1 = *(const u16x8*)&eo1[(size_t)s1 * 2048 + c];
  #pragma unroll
  for (int j0 = 0; j0 < 8; j0 += 4) {
    float4 v = *(const float4*)&out[(size_t)t * 2048 + c + j0];
    v.x += w0 * (bf2f(a0[j0+0]) + bf2f(a1[j0+0])) + w1 * (bf2f(b0[j0+0]) + bf2f(b1[j0+0]));
    v.y += w0 * (bf2f(a0[j0+1]) + bf2f(a1[j0+1])) + w1 * (bf2f(b0[j0+1]) + bf2f(b1[j0+1]));
    v.z += w0 * (bf2f(a0[j0+2]) + bf2f(a1[j0+2])) + w1 * (bf2f(b0[j0+2]) + bf2f(b1[j0+2]));
    v.w += w0 * (bf2f(a0[j0+3]) + bf2f(a1[j0+3])) + w1 * (bf2f(b0[j0+3]) + bf2f(b1[j0+3]));
    *(float4*)&out[(size_t)t * 2048 + c + j0] = v;
  }
}

// ---------------------------------------------------------------------------
extern "C" void kernel_launch(void* const* d_in, const int* in_sizes, int n_in,
                              void* d_out, int out_size, void* d_ws, size_t ws_size,
                              hipStream_t stream)
{
  const float* hidden  = (const float*)d_in[0];
  const float* enc     = (const float*)d_in[1];
  const float* img_cos = (const float*)d_in[2];
  const float* img_sin = (const float*)d_in[3];
  const float* txt_cos = (const float*)d_in[4];
  const float* txt_sin = (const float*)d_in[5];
  const float* norm1_w = (const float*)d_in[6];
  const float* norm2_w = (const float*)d_in[7];
  const float* wq      = (const float*)d_in[8];
  const float* wk      = (const float*)d_in[9];
  const float* wv      = (const float*)d_in[10];
  const float* wk_txt  = (const float*)d_in[11];
  const float* wv_txt  = (const float*)d_in[12];
  const float* wo      = (const float*)d_in[13];
  const float* q_norm_w       = (const float*)d_in[14];
  const float* k_norm_w       = (const float*)d_in[15];
  const float* added_k_norm_w = (const float*)d_in[16];
  const float* router_w       = (const float*)d_in[17];
  const float* gate_up_proj   = (const float*)d_in[18];
  const float* down_proj      = (const float*)d_in[19];
  float* out = (float*)d_out;

  char* ws = (char*)d_ws;
  size_t off = 0;
  auto alloc = [&](size_t bytes) {
    void* p = ws + off;
    off += (bytes + 255) & ~(size_t)255;
    return p;
  };
  unsigned short* wqkvT  = (unsigned short*)alloc(3072ULL * 2048 * 2);
  unsigned short* wkvtT  = (unsigned short*)alloc(1024ULL * 2048 * 2);
  unsigned short* woT    = (unsigned short*)alloc(2048ULL * 2048 * 2);
  unsigned short* gupT   = (unsigned short*)alloc(8ULL * 2048 * 2048 * 2);
  unsigned short* dnT    = (unsigned short*)alloc(8ULL * 2048 * 1024 * 2);
  unsigned short* x_bf   = (unsigned short*)alloc(2048ULL * 2048 * 2);
  unsigned short* enc_bf = (unsigned short*)alloc(1024ULL * 2048 * 2);
  unsigned short* gu0 = (unsigned short*)alloc(4096ULL * 2048 * 2);
  unsigned short* gu1 = (unsigned short*)alloc(4096ULL * 2048 * 2);
  unsigned short* qb   = (unsigned short*)alloc(2048ULL * 2048 * 2);
  unsigned short* kbuf = (unsigned short*)alloc(2ULL * 4 * 1536 * 128 * 2);
  unsigned short* vbuf = (unsigned short*)alloc(2ULL * 4 * 1536 * 128 * 2);
  unsigned short* obuf = (unsigned short*)alloc(2048ULL * 2048 * 2);
  unsigned short* act  = obuf;
  unsigned short* xt   = (unsigned short*)alloc(2048ULL * 2048 * 2);
  int*   ctrl  = (int*)alloc(64 * sizeof(int));
  int*   topi  = (int*)alloc(4096 * 4);
  float* topw  = (float*)alloc(4096 * 4);
  int*   tslot = (int*)alloc(4096 * 4);
  int*   ptok  = (int*)alloc(4096 * 4);
  unsigned short* zbuf = (unsigned short*)alloc(256);
  int* counts = ctrl, * offsets = ctrl + 16;

  hipMemsetAsync(ctrl, 0, 64, stream);
  hipMemsetAsync(zbuf, 0, 256, stream);

  const float scale = 0.08838834764831845f;  // 1/sqrt(128)

  CvtJobs jb;
  jb.src[0] = wq;     jb.dst[0] = wqkvT;                  jb.K[0] = 2048; jb.N[0] = 2048;
  jb.src[1] = wk;     jb.dst[1] = wqkvT + 2048ULL * 2048; jb.K[1] = 2048; jb.N[1] = 512;
  jb.src[2] = wv;     jb.dst[2] = wqkvT + 2560ULL * 2048; jb.K[2] = 2048; jb.N[2] = 512;
  jb.src[3] = wk_txt; jb.dst[3] = wkvtT;                  jb.K[3] = 2048; jb.N[3] = 512;
  jb.src[4] = wv_txt; jb.dst[4] = wkvtT + 512ULL * 2048;  jb.K[4] = 2048; jb.N[4] = 512;
  jb.src[5] = wo;     jb.dst[5] = woT;                    jb.K[5] = 2048; jb.N[5] = 2048;
  jb.src[6] = gate_up_proj; jb.dst[6] = gupT;             jb.K[6] = 2048; jb.N[6] = 2048;
  jb.src[7] = down_proj;    jb.dst[7] = dnT;              jb.K[7] = 1024; jb.N[7] = 2048;
  jb.off[0] = 0;     jb.off[1] = 1024;  jb.off[2] = 1280; jb.off[3] = 1536;
  jb.off[4] = 1792;  jb.off[5] = 2048;  jb.off[6] = 3072; jb.off[7] = 11264;
  jb.off[8] = 15360;
  convert_all<<<15360, 256, 0, stream>>>(jb);

  pre_norm<<<3072, 256, 0, stream>>>(hidden, norm1_w, x_bf, enc, enc_bf);

  Epi ep;
  ep.qb = qb; ep.kbuf = kbuf; ep.vbuf = vbuf;
  ep.q_nw = q_norm_w; ep.k_nw = k_norm_w; ep.kt_nw = added_k_norm_w;
  ep.icos = img_cos; ep.isin = img_sin; ep.tcos = txt_cos; ep.tsin = txt_sin;
  ep.scale = scale;

  gemm_bb<<<384, 256, 0, stream>>>(x_bf, wqkvT, nullptr, nullptr, 2048, 3072, 2048, 1, ep);
  gemm_bb<<<64, 256, 0, stream>>>(enc_bf, wkvtT, nullptr, nullptr, 1024, 1024, 2048, 2, ep);

  attn_kernel<<<256, 512, 0, stream>>>(qb, kbuf, vbuf, obuf);

  gemm_bb<<<256, 256, 0, stream>>>(obuf, woT, out, hidden, 2048, 2048, 2048, 0, ep);

  rmsnorm_router<<<2048, 256, 0, stream>>>(out, norm2_w, xt, router_w,
                                           topi, topw, counts);
  route_build<<<1, 256, 0, stream>>>(counts, offsets, topi, ptok, tslot);

  gemm_moe_256sk<<<1024, 512, 0, stream>>>(xt, gupT, gu0, gu1,
                                           counts, offsets, ptok, zbuf, 1, 2048, 2048);
  act_silu2<<<4096, 256, 0, stream>>>(gu0, gu1, act);
  gemm_moe_256sk<<<1024, 512, 0, stream>>>(act, dnT, gu0, gu1,
                                           counts, offsets, ptok, zbuf, 0, 1024, 2048);
  moe_combine2<<<2048, 256, 0, stream>>>(out, gu0, gu1, tslot, topw);
}

// Round 18
// 507.856 us; speedup vs baseline: 1.1194x; 1.0179x over previous
//
#include <hip/hip_runtime.h>

// ---------------------------------------------------------------------------
// NucleusMoEImageTransformerBlock round 18.
// B=2 SI=1024 ST=512 D=2048 H=16 KV=4 HD=128 E=8 F=1024 TOPK=2
// Round-18: convert v4 -- keep v1's proven [64][66] LDS tile, but each block
// does 2 adjacent k-subtiles with register-cached outputs (2x128B adjacent
// stores per row => ~256B effective write runs) + XCD swizzle on the convert
// grid (contiguous kt-runs per XCD => DRAM write page locality).
// Everything else identical to r17 (best-known: 513-517us).
// ---------------------------------------------------------------------------

typedef __attribute__((ext_vector_type(8))) __bf16 bf16x8;
typedef __attribute__((ext_vector_type(8))) unsigned short u16x8;
typedef __attribute__((ext_vector_type(4))) unsigned short u16x4;
typedef __attribute__((ext_vector_type(4))) float f32x4;

__device__ __forceinline__ unsigned short f2bf(float x) {
  unsigned u = __builtin_bit_cast(unsigned, x);
  u += 0x7fffu + ((u >> 16) & 1u);        // RNE
  return (unsigned short)(u >> 16);
}
__device__ __forceinline__ float bf2f(unsigned short b) {
  return __builtin_bit_cast(float, ((unsigned)b) << 16);
}

__device__ __forceinline__ void glds16(const unsigned short* g, unsigned short* l) {
  __builtin_amdgcn_global_load_lds(
      (const __attribute__((address_space(1))) void*)g,
      (__attribute__((address_space(3))) void*)l, 16, 0, 0);
}

// m204 bijective XCD chunk swizzle.
__device__ __forceinline__ int xcd_swz(int orig, int nwg) {
  int q = nwg >> 3, r = nwg & 7;
  int xcd = orig & 7, idx = orig >> 3;
  int base = (xcd < r) ? xcd * (q + 1) : r * (q + 1) + (xcd - r) * q;
  return base + idx;
}

// ---------------------------------------------------------------------------
// Batched weight convert+transpose v4: f32 [K][N] -> bf16 [N][K].
// Block = [128 k][64 n] as 2 sequential 64x64 subtiles through v1's
// [64][66] LDS; outputs register-cached, written as 2 adjacent 128B
// stores per row. Grid XCD-swizzled for write locality.
// ---------------------------------------------------------------------------
struct CvtJobs {
  const float* src[8];
  unsigned short* dst[8];
  int K[8];
  int N[8];
  int off[9];
};

__global__ __launch_bounds__(256) void convert_all(CvtJobs jb)
{
  __shared__ unsigned short T[64][66];
  const int bid = xcd_swz(blockIdx.x, gridDim.x);
  int j = 0;
  #pragma unroll
  for (int i = 0; i < 8; ++i) if (bid >= jb.off[i + 1]) j = i + 1;
  const int local = bid - jb.off[j];
  const int K = jb.K[j], N = jb.N[j];
  const int kb = K >> 7, nb = N >> 6;     // 128-k x 64-n macro tiles
  const int kt = local % kb;
  const int rest = local / kb;
  const int nt = rest % nb, zi = rest / nb;
  const float* Wz = jb.src[j] + (size_t)zi * K * N;
  unsigned short* WTz = jb.dst[j] + (size_t)zi * K * N;
  const int k0 = kt * 128, n0 = nt * 64;
  const int tid = threadIdx.x;
  const int wn = tid >> 3, wk8 = (tid & 7) * 8;   // output slots: rows wn, wn+32
  u16x8 r00, r01, r10, r11;

  // subtile 0 (k0 .. k0+63)
  #pragma unroll
  for (int i = tid; i < 64 * 16; i += 256) {
    int k = i >> 4, n4 = (i & 15) * 4;
    float4 v = *(const float4*)&Wz[(size_t)(k0 + k) * N + n0 + n4];
    T[n4 + 0][k] = f2bf(v.x);
    T[n4 + 1][k] = f2bf(v.y);
    T[n4 + 2][k] = f2bf(v.z);
    T[n4 + 3][k] = f2bf(v.w);
  }
  __syncthreads();
  r00 = *(const u16x8*)&T[wn][wk8];
  r01 = *(const u16x8*)&T[wn + 32][wk8];
  __syncthreads();

  // subtile 1 (k0+64 .. k0+127)
  #pragma unroll
  for (int i = tid; i < 64 * 16; i += 256) {
    int k = i >> 4, n4 = (i & 15) * 4;
    float4 v = *(const float4*)&Wz[(size_t)(k0 + 64 + k) * N + n0 + n4];
    T[n4 + 0][k] = f2bf(v.x);
    T[n4 + 1][k] = f2bf(v.y);
    T[n4 + 2][k] = f2bf(v.z);
    T[n4 + 3][k] = f2bf(v.w);
  }
  __syncthreads();
  r10 = *(const u16x8*)&T[wn][wk8];
  r11 = *(const u16x8*)&T[wn + 32][wk8];

  // write: 2 adjacent 128B chunks per output row
  unsigned short* row0 = WTz + (size_t)(n0 + wn) * K + k0;
  unsigned short* row1 = WTz + (size_t)(n0 + wn + 32) * K + k0;
  *(u16x8*)&row0[wk8]      = r00;
  *(u16x8*)&row0[64 + wk8] = r10;
  *(u16x8*)&row1[wk8]      = r01;
  *(u16x8*)&row1[64 + wk8] = r11;
}

// ---------------------------------------------------------------------------
// Epilogue argument bundle for gemm_bb modes 1/2.
// ---------------------------------------------------------------------------
struct Epi {
  unsigned short* qb;
  unsigned short* kbuf;
  unsigned short* vbuf;
  const float* q_nw;
  const float* k_nw;
  const float* kt_nw;
  const float* icos;
  const float* isin;
  const float* tcos;
  const float* tsin;
  float scale;
};

// ---------------------------------------------------------------------------
// Dense GEMM (modes as r13): 128x128 tile, counted-vmcnt dbuf pipeline.
// ---------------------------------------------------------------------------
__global__ __launch_bounds__(256) void gemm_bb(
    const unsigned short* __restrict__ A, const unsigned short* __restrict__ BT,
    float* __restrict__ C, const float* __restrict__ resid,
    int M, int N, int K, int mode, Epi ep)
{
  __shared__ unsigned short As[2][128 * 64];
  __shared__ unsigned short Bs[2][128 * 64];
  const int mb = M >> 7;
  const int w = xcd_swz(blockIdx.x, gridDim.x);
  const int bm = (w % mb) * 128, bn = (w / mb) * 128;
  const int tid = threadIdx.x, lane = tid & 63, wid = tid >> 6;
  const int wm = (wid >> 1) * 64, wn = (wid & 1) * 64;
  const int l16 = lane & 15, g4 = lane >> 4;
  const int rseg = lane >> 3;
  const int csw  = ((lane & 7) ^ rseg) * 8;
  const unsigned short* aSrc[4];
  const unsigned short* bSrc[4];
  #pragma unroll
  for (int p = 0; p < 4; ++p) {
    int row = (p * 4 + wid) * 8 + rseg;
    aSrc[p] = A  + (size_t)(bm + row) * K + csw;
    bSrc[p] = BT + (size_t)(bn + row) * K + csw;
  }
  f32x4 acc[4][4] = {};
  const int NT = K >> 6;
  #pragma unroll
  for (int p = 0; p < 4; ++p) glds16(aSrc[p], &As[0][(p * 4 + wid) * 512]);
  #pragma unroll
  for (int p = 0; p < 4; ++p) glds16(bSrc[p], &Bs[0][(p * 4 + wid) * 512]);
  for (int t = 0; t < NT; ++t) {
    const int cur = t & 1;
    if (t + 1 < NT) {
      const int k0 = (t + 1) << 6;
      #pragma unroll
      for (int p = 0; p < 4; ++p) glds16(aSrc[p] + k0, &As[cur ^ 1][(p * 4 + wid) * 512]);
      #pragma unroll
      for (int p = 0; p < 4; ++p) glds16(bSrc[p] + k0, &Bs[cur ^ 1][(p * 4 + wid) * 512]);
      asm volatile("s_waitcnt vmcnt(8)" ::: "memory");
    } else {
      asm volatile("s_waitcnt vmcnt(0)" ::: "memory");
    }
    __builtin_amdgcn_s_barrier();
    __builtin_amdgcn_sched_barrier(0);
    const unsigned short* ab = &As[cur][0];
    const unsigned short* bb = &Bs[cur][0];
    __builtin_amdgcn_s_setprio(1);
    #pragma unroll
    for (int ks = 0; ks < 2; ++ks) {
      bf16x8 af[4], bf[4];
      #pragma unroll
      for (int i = 0; i < 4; ++i) {
        int ra = wm + i * 16 + l16;
        int rb = wn + i * 16 + l16;
        int ch = ((ks * 4 + g4) ^ (l16 & 7)) * 8;
        af[i] = *(const bf16x8*)&ab[ra * 64 + ch];
        bf[i] = *(const bf16x8*)&bb[rb * 64 + ch];
      }
      #pragma unroll
      for (int mi = 0; mi < 4; ++mi)
        #pragma unroll
        for (int ni = 0; ni < 4; ++ni)
          acc[mi][ni] = __builtin_amdgcn_mfma_f32_16x16x32_bf16(af[mi], bf[ni], acc[mi][ni], 0, 0, 0);
    }
    __builtin_amdgcn_s_setprio(0);
    __builtin_amdgcn_sched_barrier(0);
    __builtin_amdgcn_s_barrier();
  }
  const int r4 = g4 * 4;

  if (mode == 0) {
    #pragma unroll
    for (int mi = 0; mi < 4; ++mi)
      #pragma unroll
      for (int ni = 0; ni < 4; ++ni)
        #pragma unroll
        for (int r = 0; r < 4; ++r) {
          int row = bm + wm + mi * 16 + r4 + r;
          int col = bn + wn + ni * 16 + l16;
          float v = acc[mi][ni][r];
          if (resid) v += resid[(size_t)row * N + col];
          C[(size_t)row * N + col] = v;
        }
    return;
  }

  // ---- fused head-norm / rope / relayout epilogue (modes 1,2) ----
  const int bt = bn >> 7;
  unsigned short* dst;
  const float* nw = nullptr;
  const float* cosT = nullptr;
  const float* sinT = nullptr;
  int h, NH, st, soff, vkind = 0, shift;
  float premul = 1.f;
  int S;
  if (mode == 1) {
    S = 1024; shift = 10;
    if (bt < 16)      { h = bt;      dst = ep.qb;   nw = ep.q_nw; cosT = ep.icos; sinT = ep.isin;
                        NH = 16; st = 1024; soff = 0; premul = ep.scale; }
    else if (bt < 20) { h = bt - 16; dst = ep.kbuf; nw = ep.k_nw; cosT = ep.icos; sinT = ep.isin;
                        NH = 4;  st = 1536; soff = 0; }
    else              { h = bt - 20; dst = ep.vbuf; vkind = 1; NH = 4; st = 1536; soff = 0; }
  } else {
    S = 512; shift = 9;
    if (bt < 4) { h = bt;     dst = ep.kbuf; nw = ep.kt_nw; cosT = ep.tcos; sinT = ep.tsin;
                  NH = 4; st = 1536; soff = 1024; }
    else        { h = bt - 4; dst = ep.vbuf; vkind = 1; NH = 4; st = 1536; soff = 1024; }
  }

  if (vkind) {
    #pragma unroll
    for (int mi = 0; mi < 4; ++mi)
      #pragma unroll
      for (int ni = 0; ni < 4; ++ni)
        #pragma unroll
        for (int r = 0; r < 4; ++r) {
          int row = wm + mi * 16 + r4 + r;
          int d   = wn + ni * 16 + l16;
          int token = bm + row;
          int srow = token & (S - 1), bidx = token >> shift;
          dst[((size_t)(bidx * NH + h) * st + srow + soff) * 128 + d] = f2bf(acc[mi][ni][r]);
        }
    return;
  }

  float* ssb = (float*)&As[0][0];
  float ssp[4][4];
  #pragma unroll
  for (int mi = 0; mi < 4; ++mi)
    #pragma unroll
    for (int r = 0; r < 4; ++r) {
      float v = 0.f;
      #pragma unroll
      for (int ni = 0; ni < 4; ++ni) v += acc[mi][ni][r] * acc[mi][ni][r];
      #pragma unroll
      for (int off = 1; off < 16; off <<= 1) v += __shfl_xor(v, off);
      ssp[mi][r] = v;
    }
  __syncthreads();
  if (l16 == 0) {
    #pragma unroll
    for (int mi = 0; mi < 4; ++mi)
      #pragma unroll
      for (int r = 0; r < 4; ++r)
        ssb[(wid & 1) * 128 + wm + mi * 16 + r4 + r] = ssp[mi][r];
  }
  __syncthreads();
  #pragma unroll
  for (int mi = 0; mi < 4; ++mi)
    #pragma unroll
    for (int r = 0; r < 4; ++r) {
      int row = wm + mi * 16 + r4 + r;
      float tot = ssb[row] + ssb[128 + row];
      float inv = rsqrtf(tot * (1.f / 128.f) + 1e-6f);
      int token = bm + row;
      int srow = token & (S - 1), bidx = token >> shift;
      #pragma unroll
      for (int ni = 0; ni < 4; ++ni) {
        int d = wn + ni * 16 + l16;
        float y = acc[mi][ni][r] * inv * nw[d];
        float part = __shfl_xor(y, 1);
        float c  = cosT[srow * 64 + (d >> 1)];
        float sn = sinT[srow * 64 + (d >> 1)];
        float outv = (d & 1) ? (part * sn + y * c) : (y * c - part * sn);
        dst[((size_t)(bidx * NH + h) * st + srow + soff) * 128 + d] = f2bf(outv * premul);
      }
    }
}

// ---------------------------------------------------------------------------
// Expert-batched MoE GEMM, 256x256 tile, split-K=2, counted-vmcnt dbuf,
// bf16 partial outputs. Grid 1024 = 8bm x 2kh x 8bn x 8e, XCD-swizzled.
// ---------------------------------------------------------------------------
__global__ __launch_bounds__(512, 1) void gemm_moe_256sk(
    const unsigned short* __restrict__ A, const unsigned short* __restrict__ BTall,
    unsigned short* __restrict__ C0, unsigned short* __restrict__ C1,
    const int* __restrict__ counts, const int* __restrict__ offsets,
    const int* __restrict__ pair_token, const unsigned short* __restrict__ zbuf,
    int gather, int K, int N)
{
  const int w = xcd_swz(blockIdx.x, gridDim.x);
  const int e = w >> 7;
  const int local = w & 127;
  const int bm = ((local >> 4) & 7) * 256;
  const int kh = (local >> 3) & 1;
  const int bn = (local & 7) * 256;
  const int cnt = counts[e];
  if (bm >= cnt) return;
  const int base = offsets[e];
  const int Kh = K >> 1;
  unsigned short* __restrict__ C = kh ? C1 : C0;
  __shared__ unsigned short As[2][256 * 64];
  __shared__ unsigned short Bs[2][256 * 64];
  __shared__ int rowmap[256];
  const int tid = threadIdx.x, lane = tid & 63, wid = tid >> 6;
  const int wr = wid >> 2, wc = wid & 3;
  const int l16 = lane & 15, g4 = lane >> 4;
  const int rseg = lane >> 3;
  const int csw  = ((lane & 7) ^ rseg) * 8;
  if (tid < 256) {
    int lr = bm + tid;
    rowmap[tid] = (lr < cnt) ? (gather ? pair_token[base + lr] : base + lr) : -1;
  }
  __syncthreads();
  const unsigned short* BT = BTall + (size_t)e * N * K;
  const unsigned short* aSrc[4];
  const unsigned short* bSrc[4];
  int aOk[4];
  #pragma unroll
  for (int p = 0; p < 4; ++p) {
    int row = (p * 8 + wid) * 8 + rseg;
    int tok = rowmap[row];
    aOk[p] = (tok >= 0);
    aSrc[p] = aOk[p] ? (A + (size_t)tok * K + kh * Kh + csw) : (zbuf + csw);
    bSrc[p] = BT + (size_t)(bn + row) * K + kh * Kh + csw;
  }
  f32x4 acc[8][4] = {};
  const int NT = Kh >> 6;
  #pragma unroll
  for (int p = 0; p < 4; ++p) glds16(aSrc[p], &As[0][(p * 8 + wid) * 512]);
  #pragma unroll
  for (int p = 0; p < 4; ++p) glds16(bSrc[p], &Bs[0][(p * 8 + wid) * 512]);
  for (int t = 0; t < NT; ++t) {
    const int cur = t & 1;
    if (t + 1 < NT) {
      const int k0 = (t + 1) << 6;
      #pragma unroll
      for (int p = 0; p < 4; ++p)
        glds16(aSrc[p] + (aOk[p] ? k0 : 0), &As[cur ^ 1][(p * 8 + wid) * 512]);
      #pragma unroll
      for (int p = 0; p < 4; ++p)
        glds16(bSrc[p] + k0, &Bs[cur ^ 1][(p * 8 + wid) * 512]);
      asm volatile("s_waitcnt vmcnt(8)" ::: "memory");
    } else {
      asm volatile("s_waitcnt vmcnt(0)" ::: "memory");
    }
    __builtin_amdgcn_s_barrier();
    __builtin_amdgcn_sched_barrier(0);
    const unsigned short* ab = &As[cur][0];
    const unsigned short* bb = &Bs[cur][0];
    __builtin_amdgcn_s_setprio(1);
    #pragma unroll
    for (int ks = 0; ks < 2; ++ks) {
      const int ch = ((ks * 4 + g4) ^ (l16 & 7)) * 8;
      bf16x8 bf[4];
      #pragma unroll
      for (int j = 0; j < 4; ++j)
        bf[j] = *(const bf16x8*)&bb[(wc * 64 + j * 16 + l16) * 64 + ch];
      #pragma unroll
      for (int mi = 0; mi < 8; ++mi) {
        bf16x8 af = *(const bf16x8*)&ab[(wr * 128 + mi * 16 + l16) * 64 + ch];
        #pragma unroll
        for (int ni = 0; ni < 4; ++ni)
          acc[mi][ni] = __builtin_amdgcn_mfma_f32_16x16x32_bf16(af, bf[ni], acc[mi][ni], 0, 0, 0);
      }
    }
    __builtin_amdgcn_s_setprio(0);
    __builtin_amdgcn_sched_barrier(0);
    __builtin_amdgcn_s_barrier();
  }
  const int r4 = g4 * 4;
  #pragma unroll
  for (int mi = 0; mi < 8; ++mi)
    #pragma unroll
    for (int ni = 0; ni < 4; ++ni)
      #pragma unroll
      for (int r = 0; r < 4; ++r) {
        int lrow = bm + wr * 128 + mi * 16 + r4 + r;
        int col  = bn + wc * 64 + ni * 16 + l16;
        if (lrow < cnt)
          C[(size_t)(base + lrow) * N + col] = f2bf(acc[mi][ni][r]);
      }
}

// ---------------------------------------------------------------------------
// pre_norm: rows 0..2047 rmsnorm(hidden)->x_bf; rows 2048..3071 convert enc.
// ---------------------------------------------------------------------------
__global__ __launch_bounds__(256) void pre_norm(
    const float* __restrict__ hidden, const float* __restrict__ w,
    unsigned short* __restrict__ x_bf,
    const float* __restrict__ enc, unsigned short* __restrict__ enc_bf)
{
  const int row = blockIdx.x;
  const int tid = threadIdx.x;
  if (row >= 2048) {
    const int r = row - 2048;
    const float* x = enc + (size_t)r * 2048 + tid * 8;
    unsigned short* o = enc_bf + (size_t)r * 2048 + tid * 8;
    float4 a = *(const float4*)&x[0];
    float4 b = *(const float4*)&x[4];
    o[0] = f2bf(a.x); o[1] = f2bf(a.y); o[2] = f2bf(a.z); o[3] = f2bf(a.w);
    o[4] = f2bf(b.x); o[5] = f2bf(b.y); o[6] = f2bf(b.z); o[7] = f2bf(b.w);
    return;
  }
  const float* x = hidden + (size_t)row * 2048;
  float4 a = *(const float4*)&x[tid * 8];
  float4 b = *(const float4*)&x[tid * 8 + 4];
  float s = a.x*a.x + a.y*a.y + a.z*a.z + a.w*a.w
          + b.x*b.x + b.y*b.y + b.z*b.z + b.w*b.w;
  #pragma unroll
  for (int off = 1; off < 64; off <<= 1) s += __shfl_xor(s, off);
  __shared__ float red[4];
  if ((tid & 63) == 0) red[tid >> 6] = s;
  __syncthreads();
  float inv = rsqrtf((red[0] + red[1] + red[2] + red[3]) * (1.f / 2048.f) + 1e-6f);
  float4 wa = *(const float4*)&w[tid * 8];
  float4 wb = *(const float4*)&w[tid * 8 + 4];
  unsigned short* o = x_bf + (size_t)row * 2048 + tid * 8;
  o[0] = f2bf(a.x * inv * wa.x); o[1] = f2bf(a.y * inv * wa.y);
  o[2] = f2bf(a.z * inv * wa.z); o[3] = f2bf(a.w * inv * wa.w);
  o[4] = f2bf(b.x * inv * wb.x); o[5] = f2bf(b.y * inv * wb.y);
  o[6] = f2bf(b.z * inv * wb.z); o[7] = f2bf(b.w * inv * wb.w);
}

// ---------------------------------------------------------------------------
// Fused RMSNorm(norm2) + router: bf16 xt out + exact-f32 top-2 routing.
// ---------------------------------------------------------------------------
__global__ __launch_bounds__(256) void rmsnorm_router(
    const float* __restrict__ in, const float* __restrict__ w,
    unsigned short* __restrict__ xt, const float* __restrict__ rw,
    int* __restrict__ topi, float* __restrict__ topw, int* __restrict__ counts)
{
  const int row = blockIdx.x;
  const int tid = threadIdx.x, lane = tid & 63, wid = tid >> 6;
  const float* x = in + (size_t)row * 2048;
  float4 a = *(const float4*)&x[tid * 8];
  float4 b = *(const float4*)&x[tid * 8 + 4];
  float s = a.x*a.x + a.y*a.y + a.z*a.z + a.w*a.w
          + b.x*b.x + b.y*b.y + b.z*b.z + b.w*b.w;
  #pragma unroll
  for (int off = 1; off < 64; off <<= 1) s += __shfl_xor(s, off);
  __shared__ float red[4];
  __shared__ float rl[4][8];
  if (lane == 0) red[wid] = s;
  __syncthreads();
  float inv = rsqrtf((red[0] + red[1] + red[2] + red[3]) * (1.f / 2048.f) + 1e-6f);
  float4 wa = *(const float4*)&w[tid * 8];
  float4 wb = *(const float4*)&w[tid * 8 + 4];
  float y[8] = {a.x * inv * wa.x, a.y * inv * wa.y, a.z * inv * wa.z, a.w * inv * wa.w,
                b.x * inv * wb.x, b.y * inv * wb.y, b.z * inv * wb.z, b.w * inv * wb.w};
  unsigned short* o = xt + (size_t)row * 2048 + tid * 8;
  #pragma unroll
  for (int j = 0; j < 8; ++j) o[j] = f2bf(y[j]);
  float lg[8] = {};
  #pragma unroll
  for (int j = 0; j < 8; ++j) {
    int d = tid * 8 + j;
    const float4 r0 = *(const float4*)&rw[d * 8];
    const float4 r1 = *(const float4*)&rw[d * 8 + 4];
    lg[0] += y[j] * r0.x; lg[1] += y[j] * r0.y; lg[2] += y[j] * r0.z; lg[3] += y[j] * r0.w;
    lg[4] += y[j] * r1.x; lg[5] += y[j] * r1.y; lg[6] += y[j] * r1.z; lg[7] += y[j] * r1.w;
  }
  #pragma unroll
  for (int e = 0; e < 8; ++e)
    #pragma unroll
    for (int off = 1; off < 64; off <<= 1) lg[e] += __shfl_xor(lg[e], off);
  if (lane == 0) {
    #pragma unroll
    for (int e = 0; e < 8; ++e) rl[wid][e] = lg[e];
  }
  __syncthreads();
  if (tid == 0) {
    float l[8];
    #pragma unroll
    for (int e = 0; e < 8; ++e) l[e] = rl[0][e] + rl[1][e] + rl[2][e] + rl[3][e];
    float v0 = l[0]; int e0 = 0;
    #pragma unroll
    for (int e = 1; e < 8; ++e) if (l[e] > v0) { v0 = l[e]; e0 = e; }
    float v1 = -1e30f; int e1 = 0;
    #pragma unroll
    for (int e = 0; e < 8; ++e) if (e != e0 && l[e] > v1) { v1 = l[e]; e1 = e; }
    float x1 = expf(v1 - v0);
    float w0 = 1.f / (1.f + x1);
    float w1 = x1 / (1.f + x1);
    topi[2 * row] = e0; topi[2 * row + 1] = e1;
    topw[2 * row] = w0; topw[2 * row + 1] = w1;
    atomicAdd(&counts[e0], 1);
    atomicAdd(&counts[e1], 1);
  }
}

// ---------------------------------------------------------------------------
// route_build: single block. Scan counts -> offsets, scatter via LDS atomics.
// ---------------------------------------------------------------------------
__global__ __launch_bounds__(256) void route_build(
    const int* __restrict__ counts, int* __restrict__ offsets,
    const int* __restrict__ topi,
    int* __restrict__ pair_token, int* __restrict__ token_slot)
{
  __shared__ int soff[9];
  __shared__ int sfill[8];
  const int tid = threadIdx.x;
  if (tid == 0) {
    int a = 0;
    #pragma unroll
    for (int e = 0; e < 8; ++e) { soff[e] = a; a += counts[e]; }
    soff[8] = a;
  }
  if (tid < 8) sfill[tid] = 0;
  __syncthreads();
  if (tid < 9) offsets[tid] = soff[tid];
  for (int t = tid; t < 2048; t += 256) {
    #pragma unroll
    for (int k = 0; k < 2; ++k) {
      int e = topi[2 * t + k];
      int slot = soff[e] + atomicAdd(&sfill[e], 1);
      pair_token[slot] = t;
      token_slot[2 * t + k] = slot;
    }
  }
}

// ---------------------------------------------------------------------------
// Flash attention (r12 form): 128 q-rows/block, grid 256.
// ---------------------------------------------------------------------------
__global__ __launch_bounds__(512) void attn_kernel(
    const unsigned short* __restrict__ q,
    const unsigned short* __restrict__ kbuf,
    const unsigned short* __restrict__ vbuf,
    unsigned short* __restrict__ o)
{
  const int SK = 1536;
  const int w = xcd_swz(blockIdx.x, gridDim.x);
  const int bh = w >> 3;
  const int b = bh >> 4, h = bh & 15, kvh = h >> 2;
  const int q0 = (w & 7) * 128;
  const int tid = threadIdx.x, lane = tid & 63, wid = tid >> 6;
  const int l16 = lane & 15, kb = (lane >> 4) * 8, r4 = (lane >> 4) * 4;
  __shared__ unsigned short KsL[64 * 128];
  __shared__ unsigned short VTL[128 * 64];
  __shared__ unsigned short PsL[8 * 16 * 64];
  const int sr0 = tid >> 4;
  const int scc = (tid & 15) * 8;

  const unsigned short* qrow =
      q + ((size_t)(b * 16 + h) * 1024 + q0 + wid * 16 + l16) * 128;
  bf16x8 qf[4];
  #pragma unroll
  for (int ks = 0; ks < 4; ++ks) qf[ks] = *(const bf16x8*)&qrow[ks * 32 + kb];
  float mrow[4] = {-1e30f, -1e30f, -1e30f, -1e30f};
  float lrow[4] = {0.f, 0.f, 0.f, 0.f};
  f32x4 oacc[8] = {};
  const unsigned short* kb_base = kbuf + (size_t)(b * 4 + kvh) * SK * 128;
  const unsigned short* vb_base = vbuf + (size_t)(b * 4 + kvh) * SK * 128;

  u16x8 k0[2], v0[2], k1[2], v1[2];

#define ATT_LOAD(kr, vr, kt1)                                                 \
  {                                                                           \
    _Pragma("unroll")                                                         \
    for (int i = 0; i < 2; ++i) {                                             \
      kr[i] = *(const u16x8*)&kb_base[(size_t)((kt1) + sr0 + 32 * i) * 128 + scc]; \
      vr[i] = *(const u16x8*)&vb_base[(size_t)((kt1) + sr0 + 32 * i) * 128 + scc]; \
    }                                                                         \
  }

#define ATT_STAGE(kr, vr)                                                     \
  {                                                                           \
    _Pragma("unroll")                                                         \
    for (int i = 0; i < 2; ++i) {                                             \
      int rr = sr0 + 32 * i;                                                  \
      *(u16x8*)&KsL[rr * 128 + (((scc >> 3) ^ (rr & 7)) << 3)] = kr[i];       \
      _Pragma("unroll")                                                       \
      for (int j = 0; j < 8; ++j)                                             \
        VTL[(scc + j) * 64 + ((((rr >> 3) ^ ((scc + j) >> 3)) & 7) << 3) + (rr & 7)] = vr[i][j]; \
    }                                                                         \
  }

  auto compute = [&]() {
    f32x4 sacc[4] = {};
    __builtin_amdgcn_s_setprio(1);
    #pragma unroll
    for (int ks = 0; ks < 4; ++ks) {
      #pragma unroll
      for (int ni = 0; ni < 4; ++ni) {
        int rr = ni * 16 + l16;
        bf16x8 kf = *(const bf16x8*)
            &KsL[rr * 128 + ((((ks * 32 + kb) >> 3) ^ (rr & 7)) << 3)];
        sacc[ni] = __builtin_amdgcn_mfma_f32_16x16x32_bf16(qf[ks], kf, sacc[ni], 0, 0, 0);
      }
    }
    __builtin_amdgcn_s_setprio(0);
    float pv[4][4], alpha[4];
    #pragma unroll
    for (int r = 0; r < 4; ++r) {
      float tm = fmaxf(fmaxf(sacc[0][r], sacc[1][r]), fmaxf(sacc[2][r], sacc[3][r]));
      #pragma unroll
      for (int off = 1; off < 16; off <<= 1) tm = fmaxf(tm, __shfl_xor(tm, off));
      float mn = fmaxf(mrow[r], tm);
      alpha[r] = __expf(mrow[r] - mn);
      float s = 0.f;
      #pragma unroll
      for (int ni = 0; ni < 4; ++ni) {
        float p = __expf(sacc[ni][r] - mn);
        pv[ni][r] = p; s += p;
      }
      #pragma unroll
      for (int off = 1; off < 16; off <<= 1) s += __shfl_xor(s, off);
      lrow[r] = lrow[r] * alpha[r] + s;
      mrow[r] = mn;
    }
    #pragma unroll
    for (int ni = 0; ni < 8; ++ni)
      #pragma unroll
      for (int r = 0; r < 4; ++r) oacc[ni][r] *= alpha[r];
    #pragma unroll
    for (int ni = 0; ni < 4; ++ni)
      #pragma unroll
      for (int r = 0; r < 4; ++r) {
        int row = r4 + r, col = ni * 16 + l16;
        PsL[wid * 1024 + row * 64 + ((((col >> 3) ^ (row & 7)) & 7) << 3) + (col & 7)]
            = f2bf(pv[ni][r]);
      }
    asm volatile("s_waitcnt lgkmcnt(0)" ::: "memory");
    __builtin_amdgcn_sched_barrier(0);
    __builtin_amdgcn_s_setprio(1);
    #pragma unroll
    for (int ks = 0; ks < 2; ++ks) {
      bf16x8 pf = *(const bf16x8*)
          &PsL[wid * 1024 + l16 * 64 + ((((ks * 32 + kb) >> 3) ^ (l16 & 7)) << 3)];
      #pragma unroll
      for (int ni = 0; ni < 8; ++ni) {
        int d = ni * 16 + l16;
        bf16x8 vf = *(const bf16x8*)
            &VTL[d * 64 + ((((ks * 32 + kb) >> 3) ^ ((d >> 3) & 7)) << 3)];
        oacc[ni] = __builtin_amdgcn_mfma_f32_16x16x32_bf16(pf, vf, oacc[ni], 0, 0, 0);
      }
    }
    __builtin_amdgcn_s_setprio(0);
  };

  ATT_LOAD(k0, v0, 0);
  for (int t = 0; t < 24; t += 2) {
    ATT_STAGE(k0, v0);
    ATT_LOAD(k1, v1, (t + 1) * 64);
    asm volatile("s_waitcnt lgkmcnt(0)" ::: "memory");
    __builtin_amdgcn_s_barrier();
    __builtin_amdgcn_sched_barrier(0);
    compute();
    __builtin_amdgcn_sched_barrier(0);
    __builtin_amdgcn_s_barrier();
    ATT_STAGE(k1, v1);
    if (t + 2 < 24) ATT_LOAD(k0, v0, (t + 2) * 64);
    asm volatile("s_waitcnt lgkmcnt(0)" ::: "memory");
    __builtin_amdgcn_s_barrier();
    __builtin_amdgcn_sched_barrier(0);
    compute();
    __builtin_amdgcn_sched_barrier(0);
    __builtin_amdgcn_s_barrier();
  }
#undef ATT_LOAD
#undef ATT_STAGE

  #pragma unroll
  for (int ni = 0; ni < 8; ++ni)
    #pragma unroll
    for (int r = 0; r < 4; ++r) {
      float val = oacc[ni][r] / lrow[r];
      size_t row = (size_t)b * 1024 + q0 + wid * 16 + r4 + r;
      o[row * 2048 + h * 128 + ni * 16 + l16] = f2bf(val);
    }
}

// act_silu over summed bf16 split-K partials.
__global__ __launch_bounds__(256) void act_silu2(
    const unsigned short* __restrict__ gu0, const unsigned short* __restrict__ gu1,
    unsigned short* __restrict__ act)
{
  int p = blockIdx.x;
  int c = threadIdx.x * 4;
  u16x4 g0 = *(const u16x4*)&gu0[(size_t)p * 2048 + c];
  u16x4 g1 = *(const u16x4*)&gu1[(size_t)p * 2048 + c];
  u16x4 u0 = *(const u16x4*)&gu0[(size_t)p * 2048 + 1024 + c];
  u16x4 u1 = *(const u16x4*)&gu1[(size_t)p * 2048 + 1024 + c];
  #pragma unroll
  for (int j = 0; j < 4; ++j) {
    float g = bf2f(g0[j]) + bf2f(g1[j]);
    float u = bf2f(u0[j]) + bf2f(u1[j]);
    float a = g / (1.f + __expf(-g)) * u;
    act[(size_t)p * 1024 + c + j] = f2bf(a);
  }
}

// combine over summed bf16 split-K partials.
__global__ __launch_bounds__(256) void moe_combine2(
    float* __restrict__ out, const unsigned short* __restrict__ eo0,
    const unsigned short* __restrict__ eo1,
    const int* __restrict__ token_slot, const float* __restrict__ topw)
{
  int t = blockIdx.x;
  int c = threadIdx.x * 8;
  int s0 = token_slot[2 * t], s1 = token_slot[2 * t + 1];
  float w0 = topw[2 * t], w1 = topw[2 * t + 1];
  u16x8 a0 = *(const u16x8*)&eo0[(size_t)s0 * 2048 + c];
  u16x8 a1 = *(const u16x8*)&eo1[(size_t)s0 * 2048 + c];
  u16x8 b0 = *(const u16x8*)&eo0[(size_t)s1 * 2048 + c];
  u16x8 b1 = *(const u16x8*)&eo1[(size_t)s1 * 2048 + c];
  #pragma unroll
  for (int j0 = 0; j0 < 8; j0 += 4) {
    float4 v = *(const float4*)&out[(size_t)t * 2048 + c + j0];
    v.x += w0 * (bf2f(a0[j0+0]) + bf2f(a1[j0+0])) + w1 * (bf2f(b0[j0+0]) + bf2f(b1[j0+0]));
    v.y += w0 * (bf2f(a0[j0+1]) + bf2f(a1[j0+1])) + w1 * (bf2f(b0[j0+1]) + bf2f(b1[j0+1]));
    v.z += w0 * (bf2f(a0[j0+2]) + bf2f(a1[j0+2])) + w1 * (bf2f(b0[j0+2]) + bf2f(b1[j0+2]));
    v.w += w0 * (bf2f(a0[j0+3]) + bf2f(a1[j0+3])) + w1 * (bf2f(b0[j0+3]) + bf2f(b1[j0+3]));
    *(float4*)&out[(size_t)t * 2048 + c + j0] = v;
  }
}

// ---------------------------------------------------------------------------
extern "C" void kernel_launch(void* const* d_in, const int* in_sizes, int n_in,
                              void* d_out, int out_size, void* d_ws, size_t ws_size,
                              hipStream_t stream)
{
  const float* hidden  = (const float*)d_in[0];
  const float* enc     = (const float*)d_in[1];
  const float* img_cos = (const float*)d_in[2];
  const float* img_sin = (const float*)d_in[3];
  const float* txt_cos = (const float*)d_in[4];
  const float* txt_sin = (const float*)d_in[5];
  const float* norm1_w = (const float*)d_in[6];
  const float* norm2_w = (const float*)d_in[7];
  const float* wq      = (const float*)d_in[8];
  const float* wk      = (const float*)d_in[9];
  const float* wv      = (const float*)d_in[10];
  const float* wk_txt  = (const float*)d_in[11];
  const float* wv_txt  = (const float*)d_in[12];
  const float* wo      = (const float*)d_in[13];
  const float* q_norm_w       = (const float*)d_in[14];
  const float* k_norm_w       = (const float*)d_in[15];
  const float* added_k_norm_w = (const float*)d_in[16];
  const float* router_w       = (const float*)d_in[17];
  const float* gate_up_proj   = (const float*)d_in[18];
  const float* down_proj      = (const float*)d_in[19];
  float* out = (float*)d_out;

  char* ws = (char*)d_ws;
  size_t off = 0;
  auto alloc = [&](size_t bytes) {
    void* p = ws + off;
    off += (bytes + 255) & ~(size_t)255;
    return p;
  };
  unsigned short* wqkvT  = (unsigned short*)alloc(3072ULL * 2048 * 2);
  unsigned short* wkvtT  = (unsigned short*)alloc(1024ULL * 2048 * 2);
  unsigned short* woT    = (unsigned short*)alloc(2048ULL * 2048 * 2);
  unsigned short* gupT   = (unsigned short*)alloc(8ULL * 2048 * 2048 * 2);
  unsigned short* dnT    = (unsigned short*)alloc(8ULL * 2048 * 1024 * 2);
  unsigned short* x_bf   = (unsigned short*)alloc(2048ULL * 2048 * 2);
  unsigned short* enc_bf = (unsigned short*)alloc(1024ULL * 2048 * 2);
  unsigned short* gu0 = (unsigned short*)alloc(4096ULL * 2048 * 2);
  unsigned short* gu1 = (unsigned short*)alloc(4096ULL * 2048 * 2);
  unsigned short* qb   = (unsigned short*)alloc(2048ULL * 2048 * 2);
  unsigned short* kbuf = (unsigned short*)alloc(2ULL * 4 * 1536 * 128 * 2);
  unsigned short* vbuf = (unsigned short*)alloc(2ULL * 4 * 1536 * 128 * 2);
  unsigned short* obuf = (unsigned short*)alloc(2048ULL * 2048 * 2);
  unsigned short* act  = obuf;
  unsigned short* xt   = (unsigned short*)alloc(2048ULL * 2048 * 2);
  int*   ctrl  = (int*)alloc(64 * sizeof(int));
  int*   topi  = (int*)alloc(4096 * 4);
  float* topw  = (float*)alloc(4096 * 4);
  int*   tslot = (int*)alloc(4096 * 4);
  int*   ptok  = (int*)alloc(4096 * 4);
  unsigned short* zbuf = (unsigned short*)alloc(256);
  int* counts = ctrl, * offsets = ctrl + 16;

  hipMemsetAsync(ctrl, 0, 64, stream);
  hipMemsetAsync(zbuf, 0, 256, stream);

  const float scale = 0.08838834764831845f;  // 1/sqrt(128)

  CvtJobs jb;
  jb.src[0] = wq;     jb.dst[0] = wqkvT;                  jb.K[0] = 2048; jb.N[0] = 2048;
  jb.src[1] = wk;     jb.dst[1] = wqkvT + 2048ULL * 2048; jb.K[1] = 2048; jb.N[1] = 512;
  jb.src[2] = wv;     jb.dst[2] = wqkvT + 2560ULL * 2048; jb.K[2] = 2048; jb.N[2] = 512;
  jb.src[3] = wk_txt; jb.dst[3] = wkvtT;                  jb.K[3] = 2048; jb.N[3] = 512;
  jb.src[4] = wv_txt; jb.dst[4] = wkvtT + 512ULL * 2048;  jb.K[4] = 2048; jb.N[4] = 512;
  jb.src[5] = wo;     jb.dst[5] = woT;                    jb.K[5] = 2048; jb.N[5] = 2048;
  jb.src[6] = gate_up_proj; jb.dst[6] = gupT;             jb.K[6] = 2048; jb.N[6] = 2048;
  jb.src[7] = down_proj;    jb.dst[7] = dnT;              jb.K[7] = 1024; jb.N[7] = 2048;
  // 128k x 64n tiles: (K/128)*(N/64)*Z = 512, 128,128,128,128, 512, 4096, 2048
  jb.off[0] = 0;    jb.off[1] = 512;  jb.off[2] = 640;  jb.off[3] = 768;
  jb.off[4] = 896;  jb.off[5] = 1024; jb.off[6] = 1536; jb.off[7] = 5632;
  jb.off[8] = 7680;
  convert_all<<<7680, 256, 0, stream>>>(jb);

  pre_norm<<<3072, 256, 0, stream>>>(hidden, norm1_w, x_bf, enc, enc_bf);

  Epi ep;
  ep.qb = qb; ep.kbuf = kbuf; ep.vbuf = vbuf;
  ep.q_nw = q_norm_w; ep.k_nw = k_norm_w; ep.kt_nw = added_k_norm_w;
  ep.icos = img_cos; ep.isin = img_sin; ep.tcos = txt_cos; ep.tsin = txt_sin;
  ep.scale = scale;

  gemm_bb<<<384, 256, 0, stream>>>(x_bf, wqkvT, nullptr, nullptr, 2048, 3072, 2048, 1, ep);
  gemm_bb<<<64, 256, 0, stream>>>(enc_bf, wkvtT, nullptr, nullptr, 1024, 1024, 2048, 2, ep);

  attn_kernel<<<256, 512, 0, stream>>>(qb, kbuf, vbuf, obuf);

  gemm_bb<<<256, 256, 0, stream>>>(obuf, woT, out, hidden, 2048, 2048, 2048, 0, ep);

  rmsnorm_router<<<2048, 256, 0, stream>>>(out, norm2_w, xt, router_w,
                                           topi, topw, counts);
  route_build<<<1, 256, 0, stream>>>(counts, offsets, topi, ptok, tslot);

  gemm_moe_256sk<<<1024, 512, 0, stream>>>(xt, gupT, gu0, gu1,
                                           counts, offsets, ptok, zbuf, 1, 2048, 2048);
  act_silu2<<<4096, 256, 0, stream>>>(gu0, gu1, act);
  gemm_moe_256sk<<<1024, 512, 0, stream>>>(act, dnT, gu0, gu1,
                                           counts, offsets, ptok, zbuf, 0, 1024, 2048);
  moe_combine2<<<2048, 256, 0, stream>>>(out, gu0, gu1, tslot, topw);
}

// Round 19
// 476.490 us; speedup vs baseline: 1.1931x; 1.0658x over previous
//
#include <hip/hip_runtime.h>

// ---------------------------------------------------------------------------
// NucleusMoEImageTransformerBlock round 19.
// B=2 SI=1024 ST=512 D=2048 H=16 KV=4 HD=128 E=8 F=1024 TOPK=2
// Round-19: launch-merges only (convert at its ~3.7TB/s L3-BW roofline per
// r15/r18 variant sweep): (1) pre_norm folded into convert_all tail blocks;
// (2) qkv+kvt dense GEMMs merged into one 448-block launch; (3) nontemporal
// convert stores (falsification probe, expected ~null). 12 -> 10 dispatches.
// ---------------------------------------------------------------------------

typedef __attribute__((ext_vector_type(8))) __bf16 bf16x8;
typedef __attribute__((ext_vector_type(8))) unsigned short u16x8;
typedef __attribute__((ext_vector_type(4))) unsigned short u16x4;
typedef __attribute__((ext_vector_type(4))) float f32x4;

__device__ __forceinline__ unsigned short f2bf(float x) {
  unsigned u = __builtin_bit_cast(unsigned, x);
  u += 0x7fffu + ((u >> 16) & 1u);        // RNE
  return (unsigned short)(u >> 16);
}
__device__ __forceinline__ float bf2f(unsigned short b) {
  return __builtin_bit_cast(float, ((unsigned)b) << 16);
}

__device__ __forceinline__ void glds16(const unsigned short* g, unsigned short* l) {
  __builtin_amdgcn_global_load_lds(
      (const __attribute__((address_space(1))) void*)g,
      (__attribute__((address_space(3))) void*)l, 16, 0, 0);
}

// m204 bijective XCD chunk swizzle.
__device__ __forceinline__ int xcd_swz(int orig, int nwg) {
  int q = nwg >> 3, r = nwg & 7;
  int xcd = orig & 7, idx = orig >> 3;
  int base = (xcd < r) ? xcd * (q + 1) : r * (q + 1) + (xcd - r) * q;
  return base + idx;
}

// ---------------------------------------------------------------------------
// convert_all + pre_norm tail. Blocks [0,7680): weight convert v4 (128k x
// 64n, register-cached outputs, nontemporal stores). Blocks [7680,10752):
// pre_norm rows (0..2047 rmsnorm(hidden), 2048..3071 enc convert).
// ---------------------------------------------------------------------------
struct CvtJobs {
  const float* src[8];
  unsigned short* dst[8];
  int K[8];
  int N[8];
  int off[9];
};

__global__ __launch_bounds__(256) void convert_all(
    CvtJobs jb,
    const float* __restrict__ hidden, const float* __restrict__ n1w,
    unsigned short* __restrict__ x_bf,
    const float* __restrict__ enc, unsigned short* __restrict__ enc_bf)
{
  __shared__ unsigned short T[64][66];
  __shared__ float red[4];
  const int tid = threadIdx.x;
  const int bid = xcd_swz(blockIdx.x, gridDim.x);

  if (bid >= 7680) {
    // ---------------- pre_norm tail ----------------
    const int row = bid - 7680;
    if (row >= 2048) {
      const int r = row - 2048;
      const float* x = enc + (size_t)r * 2048 + tid * 8;
      unsigned short* o = enc_bf + (size_t)r * 2048 + tid * 8;
      float4 a = *(const float4*)&x[0];
      float4 b = *(const float4*)&x[4];
      o[0] = f2bf(a.x); o[1] = f2bf(a.y); o[2] = f2bf(a.z); o[3] = f2bf(a.w);
      o[4] = f2bf(b.x); o[5] = f2bf(b.y); o[6] = f2bf(b.z); o[7] = f2bf(b.w);
      return;
    }
    const float* x = hidden + (size_t)row * 2048;
    float4 a = *(const float4*)&x[tid * 8];
    float4 b = *(const float4*)&x[tid * 8 + 4];
    float s = a.x*a.x + a.y*a.y + a.z*a.z + a.w*a.w
            + b.x*b.x + b.y*b.y + b.z*b.z + b.w*b.w;
    #pragma unroll
    for (int off = 1; off < 64; off <<= 1) s += __shfl_xor(s, off);
    if ((tid & 63) == 0) red[tid >> 6] = s;
    __syncthreads();
    float inv = rsqrtf((red[0] + red[1] + red[2] + red[3]) * (1.f / 2048.f) + 1e-6f);
    float4 wa = *(const float4*)&n1w[tid * 8];
    float4 wb = *(const float4*)&n1w[tid * 8 + 4];
    unsigned short* o = x_bf + (size_t)row * 2048 + tid * 8;
    o[0] = f2bf(a.x * inv * wa.x); o[1] = f2bf(a.y * inv * wa.y);
    o[2] = f2bf(a.z * inv * wa.z); o[3] = f2bf(a.w * inv * wa.w);
    o[4] = f2bf(b.x * inv * wb.x); o[5] = f2bf(b.y * inv * wb.y);
    o[6] = f2bf(b.z * inv * wb.z); o[7] = f2bf(b.w * inv * wb.w);
    return;
  }

  // ---------------- weight convert v4 ----------------
  int j = 0;
  #pragma unroll
  for (int i = 0; i < 8; ++i) if (bid >= jb.off[i + 1]) j = i + 1;
  const int local = bid - jb.off[j];
  const int K = jb.K[j], N = jb.N[j];
  const int kb = K >> 7, nb = N >> 6;     // 128-k x 64-n macro tiles
  const int kt = local % kb;
  const int rest = local / kb;
  const int nt = rest % nb, zi = rest / nb;
  const float* Wz = jb.src[j] + (size_t)zi * K * N;
  unsigned short* WTz = jb.dst[j] + (size_t)zi * K * N;
  const int k0 = kt * 128, n0 = nt * 64;
  const int wn = tid >> 3, wk8 = (tid & 7) * 8;
  u16x8 r00, r01, r10, r11;

  #pragma unroll
  for (int i = tid; i < 64 * 16; i += 256) {
    int k = i >> 4, n4 = (i & 15) * 4;
    float4 v = *(const float4*)&Wz[(size_t)(k0 + k) * N + n0 + n4];
    T[n4 + 0][k] = f2bf(v.x);
    T[n4 + 1][k] = f2bf(v.y);
    T[n4 + 2][k] = f2bf(v.z);
    T[n4 + 3][k] = f2bf(v.w);
  }
  __syncthreads();
  r00 = *(const u16x8*)&T[wn][wk8];
  r01 = *(const u16x8*)&T[wn + 32][wk8];
  __syncthreads();

  #pragma unroll
  for (int i = tid; i < 64 * 16; i += 256) {
    int k = i >> 4, n4 = (i & 15) * 4;
    float4 v = *(const float4*)&Wz[(size_t)(k0 + 64 + k) * N + n0 + n4];
    T[n4 + 0][k] = f2bf(v.x);
    T[n4 + 1][k] = f2bf(v.y);
    T[n4 + 2][k] = f2bf(v.z);
    T[n4 + 3][k] = f2bf(v.w);
  }
  __syncthreads();
  r10 = *(const u16x8*)&T[wn][wk8];
  r11 = *(const u16x8*)&T[wn + 32][wk8];

  unsigned short* row0 = WTz + (size_t)(n0 + wn) * K + k0;
  unsigned short* row1 = WTz + (size_t)(n0 + wn + 32) * K + k0;
  __builtin_nontemporal_store(r00, (u16x8*)&row0[wk8]);
  __builtin_nontemporal_store(r10, (u16x8*)&row0[64 + wk8]);
  __builtin_nontemporal_store(r01, (u16x8*)&row1[wk8]);
  __builtin_nontemporal_store(r11, (u16x8*)&row1[64 + wk8]);
}

// ---------------------------------------------------------------------------
// Epilogue argument bundle for gemm_bb modes 1/2.
// ---------------------------------------------------------------------------
struct Epi {
  unsigned short* qb;
  unsigned short* kbuf;
  unsigned short* vbuf;
  const float* q_nw;
  const float* k_nw;
  const float* kt_nw;
  const float* icos;
  const float* isin;
  const float* tcos;
  const float* tsin;
  float scale;
};

// ---------------------------------------------------------------------------
// Dense GEMM: counted-vmcnt dbuf pipeline. Optional second config (A2/BT2,
// M2/N2) selected for blocks >= split (merged qkv+kvt launch).
// ---------------------------------------------------------------------------
__global__ __launch_bounds__(256) void gemm_bb(
    const unsigned short* __restrict__ A, const unsigned short* __restrict__ BT,
    float* __restrict__ C, const float* __restrict__ resid,
    int M, int N, int K, int mode, Epi ep,
    const unsigned short* __restrict__ A2, const unsigned short* __restrict__ BT2,
    int M2, int N2, int split)
{
  __shared__ unsigned short As[2][128 * 64];
  __shared__ unsigned short Bs[2][128 * 64];
  int w = xcd_swz(blockIdx.x, gridDim.x);
  const unsigned short* Ap = A;
  const unsigned short* Bp = BT;
  int Me = M, Ne = N, mode_eff = mode;
  if (split && w >= split) {
    Ap = A2; Bp = BT2; Me = M2; Ne = N2; mode_eff = 2; w -= split;
  }
  const int mb = Me >> 7;
  const int bm = (w % mb) * 128, bn = (w / mb) * 128;
  const int tid = threadIdx.x, lane = tid & 63, wid = tid >> 6;
  const int wm = (wid >> 1) * 64, wn = (wid & 1) * 64;
  const int l16 = lane & 15, g4 = lane >> 4;
  const int rseg = lane >> 3;
  const int csw  = ((lane & 7) ^ rseg) * 8;
  const unsigned short* aSrc[4];
  const unsigned short* bSrc[4];
  #pragma unroll
  for (int p = 0; p < 4; ++p) {
    int row = (p * 4 + wid) * 8 + rseg;
    aSrc[p] = Ap + (size_t)(bm + row) * K + csw;
    bSrc[p] = Bp + (size_t)(bn + row) * K + csw;
  }
  f32x4 acc[4][4] = {};
  const int NT = K >> 6;
  #pragma unroll
  for (int p = 0; p < 4; ++p) glds16(aSrc[p], &As[0][(p * 4 + wid) * 512]);
  #pragma unroll
  for (int p = 0; p < 4; ++p) glds16(bSrc[p], &Bs[0][(p * 4 + wid) * 512]);
  for (int t = 0; t < NT; ++t) {
    const int cur = t & 1;
    if (t + 1 < NT) {
      const int k0 = (t + 1) << 6;
      #pragma unroll
      for (int p = 0; p < 4; ++p) glds16(aSrc[p] + k0, &As[cur ^ 1][(p * 4 + wid) * 512]);
      #pragma unroll
      for (int p = 0; p < 4; ++p) glds16(bSrc[p] + k0, &Bs[cur ^ 1][(p * 4 + wid) * 512]);
      asm volatile("s_waitcnt vmcnt(8)" ::: "memory");
    } else {
      asm volatile("s_waitcnt vmcnt(0)" ::: "memory");
    }
    __builtin_amdgcn_s_barrier();
    __builtin_amdgcn_sched_barrier(0);
    const unsigned short* ab = &As[cur][0];
    const unsigned short* bb = &Bs[cur][0];
    __builtin_amdgcn_s_setprio(1);
    #pragma unroll
    for (int ks = 0; ks < 2; ++ks) {
      bf16x8 af[4], bf[4];
      #pragma unroll
      for (int i = 0; i < 4; ++i) {
        int ra = wm + i * 16 + l16;
        int rb = wn + i * 16 + l16;
        int ch = ((ks * 4 + g4) ^ (l16 & 7)) * 8;
        af[i] = *(const bf16x8*)&ab[ra * 64 + ch];
        bf[i] = *(const bf16x8*)&bb[rb * 64 + ch];
      }
      #pragma unroll
      for (int mi = 0; mi < 4; ++mi)
        #pragma unroll
        for (int ni = 0; ni < 4; ++ni)
          acc[mi][ni] = __builtin_amdgcn_mfma_f32_16x16x32_bf16(af[mi], bf[ni], acc[mi][ni], 0, 0, 0);
    }
    __builtin_amdgcn_s_setprio(0);
    __builtin_amdgcn_sched_barrier(0);
    __builtin_amdgcn_s_barrier();
  }
  const int r4 = g4 * 4;

  if (mode_eff == 0) {
    #pragma unroll
    for (int mi = 0; mi < 4; ++mi)
      #pragma unroll
      for (int ni = 0; ni < 4; ++ni)
        #pragma unroll
        for (int r = 0; r < 4; ++r) {
          int row = bm + wm + mi * 16 + r4 + r;
          int col = bn + wn + ni * 16 + l16;
          float v = acc[mi][ni][r];
          if (resid) v += resid[(size_t)row * Ne + col];
          C[(size_t)row * Ne + col] = v;
        }
    return;
  }

  // ---- fused head-norm / rope / relayout epilogue (modes 1,2) ----
  const int bt = bn >> 7;
  unsigned short* dst;
  const float* nw = nullptr;
  const float* cosT = nullptr;
  const float* sinT = nullptr;
  int h, NH, st, soff, vkind = 0, shift;
  float premul = 1.f;
  int S;
  if (mode_eff == 1) {
    S = 1024; shift = 10;
    if (bt < 16)      { h = bt;      dst = ep.qb;   nw = ep.q_nw; cosT = ep.icos; sinT = ep.isin;
                        NH = 16; st = 1024; soff = 0; premul = ep.scale; }
    else if (bt < 20) { h = bt - 16; dst = ep.kbuf; nw = ep.k_nw; cosT = ep.icos; sinT = ep.isin;
                        NH = 4;  st = 1536; soff = 0; }
    else              { h = bt - 20; dst = ep.vbuf; vkind = 1; NH = 4; st = 1536; soff = 0; }
  } else {
    S = 512; shift = 9;
    if (bt < 4) { h = bt;     dst = ep.kbuf; nw = ep.kt_nw; cosT = ep.tcos; sinT = ep.tsin;
                  NH = 4; st = 1536; soff = 1024; }
    else        { h = bt - 4; dst = ep.vbuf; vkind = 1; NH = 4; st = 1536; soff = 1024; }
  }

  if (vkind) {
    #pragma unroll
    for (int mi = 0; mi < 4; ++mi)
      #pragma unroll
      for (int ni = 0; ni < 4; ++ni)
        #pragma unroll
        for (int r = 0; r < 4; ++r) {
          int row = wm + mi * 16 + r4 + r;
          int d   = wn + ni * 16 + l16;
          int token = bm + row;
          int srow = token & (S - 1), bidx = token >> shift;
          dst[((size_t)(bidx * NH + h) * st + srow + soff) * 128 + d] = f2bf(acc[mi][ni][r]);
        }
    return;
  }

  float* ssb = (float*)&As[0][0];
  float ssp[4][4];
  #pragma unroll
  for (int mi = 0; mi < 4; ++mi)
    #pragma unroll
    for (int r = 0; r < 4; ++r) {
      float v = 0.f;
      #pragma unroll
      for (int ni = 0; ni < 4; ++ni) v += acc[mi][ni][r] * acc[mi][ni][r];
      #pragma unroll
      for (int off = 1; off < 16; off <<= 1) v += __shfl_xor(v, off);
      ssp[mi][r] = v;
    }
  __syncthreads();
  if (l16 == 0) {
    #pragma unroll
    for (int mi = 0; mi < 4; ++mi)
      #pragma unroll
      for (int r = 0; r < 4; ++r)
        ssb[(wid & 1) * 128 + wm + mi * 16 + r4 + r] = ssp[mi][r];
  }
  __syncthreads();
  #pragma unroll
  for (int mi = 0; mi < 4; ++mi)
    #pragma unroll
    for (int r = 0; r < 4; ++r) {
      int row = wm + mi * 16 + r4 + r;
      float tot = ssb[row] + ssb[128 + row];
      float inv = rsqrtf(tot * (1.f / 128.f) + 1e-6f);
      int token = bm + row;
      int srow = token & (S - 1), bidx = token >> shift;
      #pragma unroll
      for (int ni = 0; ni < 4; ++ni) {
        int d = wn + ni * 16 + l16;
        float y = acc[mi][ni][r] * inv * nw[d];
        float part = __shfl_xor(y, 1);
        float c  = cosT[srow * 64 + (d >> 1)];
        float sn = sinT[srow * 64 + (d >> 1)];
        float outv = (d & 1) ? (part * sn + y * c) : (y * c - part * sn);
        dst[((size_t)(bidx * NH + h) * st + srow + soff) * 128 + d] = f2bf(outv * premul);
      }
    }
}

// ---------------------------------------------------------------------------
// Expert-batched MoE GEMM, 256x256 tile, split-K=2, counted-vmcnt dbuf,
// bf16 partial outputs. Grid 1024 = 8bm x 2kh x 8bn x 8e, XCD-swizzled.
// ---------------------------------------------------------------------------
__global__ __launch_bounds__(512, 1) void gemm_moe_256sk(
    const unsigned short* __restrict__ A, const unsigned short* __restrict__ BTall,
    unsigned short* __restrict__ C0, unsigned short* __restrict__ C1,
    const int* __restrict__ counts, const int* __restrict__ offsets,
    const int* __restrict__ pair_token, const unsigned short* __restrict__ zbuf,
    int gather, int K, int N)
{
  const int w = xcd_swz(blockIdx.x, gridDim.x);
  const int e = w >> 7;
  const int local = w & 127;
  const int bm = ((local >> 4) & 7) * 256;
  const int kh = (local >> 3) & 1;
  const int bn = (local & 7) * 256;
  const int cnt = counts[e];
  if (bm >= cnt) return;
  const int base = offsets[e];
  const int Kh = K >> 1;
  unsigned short* __restrict__ C = kh ? C1 : C0;
  __shared__ unsigned short As[2][256 * 64];
  __shared__ unsigned short Bs[2][256 * 64];
  __shared__ int rowmap[256];
  const int tid = threadIdx.x, lane = tid & 63, wid = tid >> 6;
  const int wr = wid >> 2, wc = wid & 3;
  const int l16 = lane & 15, g4 = lane >> 4;
  const int rseg = lane >> 3;
  const int csw  = ((lane & 7) ^ rseg) * 8;
  if (tid < 256) {
    int lr = bm + tid;
    rowmap[tid] = (lr < cnt) ? (gather ? pair_token[base + lr] : base + lr) : -1;
  }
  __syncthreads();
  const unsigned short* BT = BTall + (size_t)e * N * K;
  const unsigned short* aSrc[4];
  const unsigned short* bSrc[4];
  int aOk[4];
  #pragma unroll
  for (int p = 0; p < 4; ++p) {
    int row = (p * 8 + wid) * 8 + rseg;
    int tok = rowmap[row];
    aOk[p] = (tok >= 0);
    aSrc[p] = aOk[p] ? (A + (size_t)tok * K + kh * Kh + csw) : (zbuf + csw);
    bSrc[p] = BT + (size_t)(bn + row) * K + kh * Kh + csw;
  }
  f32x4 acc[8][4] = {};
  const int NT = Kh >> 6;
  #pragma unroll
  for (int p = 0; p < 4; ++p) glds16(aSrc[p], &As[0][(p * 8 + wid) * 512]);
  #pragma unroll
  for (int p = 0; p < 4; ++p) glds16(bSrc[p], &Bs[0][(p * 8 + wid) * 512]);
  for (int t = 0; t < NT; ++t) {
    const int cur = t & 1;
    if (t + 1 < NT) {
      const int k0 = (t + 1) << 6;
      #pragma unroll
      for (int p = 0; p < 4; ++p)
        glds16(aSrc[p] + (aOk[p] ? k0 : 0), &As[cur ^ 1][(p * 8 + wid) * 512]);
      #pragma unroll
      for (int p = 0; p < 4; ++p)
        glds16(bSrc[p] + k0, &Bs[cur ^ 1][(p * 8 + wid) * 512]);
      asm volatile("s_waitcnt vmcnt(8)" ::: "memory");
    } else {
      asm volatile("s_waitcnt vmcnt(0)" ::: "memory");
    }
    __builtin_amdgcn_s_barrier();
    __builtin_amdgcn_sched_barrier(0);
    const unsigned short* ab = &As[cur][0];
    const unsigned short* bb = &Bs[cur][0];
    __builtin_amdgcn_s_setprio(1);
    #pragma unroll
    for (int ks = 0; ks < 2; ++ks) {
      const int ch = ((ks * 4 + g4) ^ (l16 & 7)) * 8;
      bf16x8 bf[4];
      #pragma unroll
      for (int j = 0; j < 4; ++j)
        bf[j] = *(const bf16x8*)&bb[(wc * 64 + j * 16 + l16) * 64 + ch];
      #pragma unroll
      for (int mi = 0; mi < 8; ++mi) {
        bf16x8 af = *(const bf16x8*)&ab[(wr * 128 + mi * 16 + l16) * 64 + ch];
        #pragma unroll
        for (int ni = 0; ni < 4; ++ni)
          acc[mi][ni] = __builtin_amdgcn_mfma_f32_16x16x32_bf16(af, bf[ni], acc[mi][ni], 0, 0, 0);
      }
    }
    __builtin_amdgcn_s_setprio(0);
    __builtin_amdgcn_sched_barrier(0);
    __builtin_amdgcn_s_barrier();
  }
  const int r4 = g4 * 4;
  #pragma unroll
  for (int mi = 0; mi < 8; ++mi)
    #pragma unroll
    for (int ni = 0; ni < 4; ++ni)
      #pragma unroll
      for (int r = 0; r < 4; ++r) {
        int lrow = bm + wr * 128 + mi * 16 + r4 + r;
        int col  = bn + wc * 64 + ni * 16 + l16;
        if (lrow < cnt)
          C[(size_t)(base + lrow) * N + col] = f2bf(acc[mi][ni][r]);
      }
}

// ---------------------------------------------------------------------------
// Fused RMSNorm(norm2) + router: bf16 xt out + exact-f32 top-2 routing.
// ---------------------------------------------------------------------------
__global__ __launch_bounds__(256) void rmsnorm_router(
    const float* __restrict__ in, const float* __restrict__ w,
    unsigned short* __restrict__ xt, const float* __restrict__ rw,
    int* __restrict__ topi, float* __restrict__ topw, int* __restrict__ counts)
{
  const int row = blockIdx.x;
  const int tid = threadIdx.x, lane = tid & 63, wid = tid >> 6;
  const float* x = in + (size_t)row * 2048;
  float4 a = *(const float4*)&x[tid * 8];
  float4 b = *(const float4*)&x[tid * 8 + 4];
  float s = a.x*a.x + a.y*a.y + a.z*a.z + a.w*a.w
          + b.x*b.x + b.y*b.y + b.z*b.z + b.w*b.w;
  #pragma unroll
  for (int off = 1; off < 64; off <<= 1) s += __shfl_xor(s, off);
  __shared__ float red[4];
  __shared__ float rl[4][8];
  if (lane == 0) red[wid] = s;
  __syncthreads();
  float inv = rsqrtf((red[0] + red[1] + red[2] + red[3]) * (1.f / 2048.f) + 1e-6f);
  float4 wa = *(const float4*)&w[tid * 8];
  float4 wb = *(const float4*)&w[tid * 8 + 4];
  float y[8] = {a.x * inv * wa.x, a.y * inv * wa.y, a.z * inv * wa.z, a.w * inv * wa.w,
                b.x * inv * wb.x, b.y * inv * wb.y, b.z * inv * wb.z, b.w * inv * wb.w};
  unsigned short* o = xt + (size_t)row * 2048 + tid * 8;
  #pragma unroll
  for (int j = 0; j < 8; ++j) o[j] = f2bf(y[j]);
  float lg[8] = {};
  #pragma unroll
  for (int j = 0; j < 8; ++j) {
    int d = tid * 8 + j;
    const float4 r0 = *(const float4*)&rw[d * 8];
    const float4 r1 = *(const float4*)&rw[d * 8 + 4];
    lg[0] += y[j] * r0.x; lg[1] += y[j] * r0.y; lg[2] += y[j] * r0.z; lg[3] += y[j] * r0.w;
    lg[4] += y[j] * r1.x; lg[5] += y[j] * r1.y; lg[6] += y[j] * r1.z; lg[7] += y[j] * r1.w;
  }
  #pragma unroll
  for (int e = 0; e < 8; ++e)
    #pragma unroll
    for (int off = 1; off < 64; off <<= 1) lg[e] += __shfl_xor(lg[e], off);
  if (lane == 0) {
    #pragma unroll
    for (int e = 0; e < 8; ++e) rl[wid][e] = lg[e];
  }
  __syncthreads();
  if (tid == 0) {
    float l[8];
    #pragma unroll
    for (int e = 0; e < 8; ++e) l[e] = rl[0][e] + rl[1][e] + rl[2][e] + rl[3][e];
    float v0 = l[0]; int e0 = 0;
    #pragma unroll
    for (int e = 1; e < 8; ++e) if (l[e] > v0) { v0 = l[e]; e0 = e; }
    float v1 = -1e30f; int e1 = 0;
    #pragma unroll
    for (int e = 0; e < 8; ++e) if (e != e0 && l[e] > v1) { v1 = l[e]; e1 = e; }
    float x1 = expf(v1 - v0);
    float w0 = 1.f / (1.f + x1);
    float w1 = x1 / (1.f + x1);
    topi[2 * row] = e0; topi[2 * row + 1] = e1;
    topw[2 * row] = w0; topw[2 * row + 1] = w1;
    atomicAdd(&counts[e0], 1);
    atomicAdd(&counts[e1], 1);
  }
}

// ---------------------------------------------------------------------------
// route_build: single block. Scan counts -> offsets, scatter via LDS atomics.
// ---------------------------------------------------------------------------
__global__ __launch_bounds__(256) void route_build(
    const int* __restrict__ counts, int* __restrict__ offsets,
    const int* __restrict__ topi,
    int* __restrict__ pair_token, int* __restrict__ token_slot)
{
  __shared__ int soff[9];
  __shared__ int sfill[8];
  const int tid = threadIdx.x;
  if (tid == 0) {
    int a = 0;
    #pragma unroll
    for (int e = 0; e < 8; ++e) { soff[e] = a; a += counts[e]; }
    soff[8] = a;
  }
  if (tid < 8) sfill[tid] = 0;
  __syncthreads();
  if (tid < 9) offsets[tid] = soff[tid];
  for (int t = tid; t < 2048; t += 256) {
    #pragma unroll
    for (int k = 0; k < 2; ++k) {
      int e = topi[2 * t + k];
      int slot = soff[e] + atomicAdd(&sfill[e], 1);
      pair_token[slot] = t;
      token_slot[2 * t + k] = slot;
    }
  }
}

// ---------------------------------------------------------------------------
// Flash attention (r12 form): 128 q-rows/block, grid 256.
// ---------------------------------------------------------------------------
__global__ __launch_bounds__(512) void attn_kernel(
    const unsigned short* __restrict__ q,
    const unsigned short* __restrict__ kbuf,
    const unsigned short* __restrict__ vbuf,
    unsigned short* __restrict__ o)
{
  const int SK = 1536;
  const int w = xcd_swz(blockIdx.x, gridDim.x);
  const int bh = w >> 3;
  const int b = bh >> 4, h = bh & 15, kvh = h >> 2;
  const int q0 = (w & 7) * 128;
  const int tid = threadIdx.x, lane = tid & 63, wid = tid >> 6;
  const int l16 = lane & 15, kb = (lane >> 4) * 8, r4 = (lane >> 4) * 4;
  __shared__ unsigned short KsL[64 * 128];
  __shared__ unsigned short VTL[128 * 64];
  __shared__ unsigned short PsL[8 * 16 * 64];
  const int sr0 = tid >> 4;
  const int scc = (tid & 15) * 8;

  const unsigned short* qrow =
      q + ((size_t)(b * 16 + h) * 1024 + q0 + wid * 16 + l16) * 128;
  bf16x8 qf[4];
  #pragma unroll
  for (int ks = 0; ks < 4; ++ks) qf[ks] = *(const bf16x8*)&qrow[ks * 32 + kb];
  float mrow[4] = {-1e30f, -1e30f, -1e30f, -1e30f};
  float lrow[4] = {0.f, 0.f, 0.f, 0.f};
  f32x4 oacc[8] = {};
  const unsigned short* kb_base = kbuf + (size_t)(b * 4 + kvh) * SK * 128;
  const unsigned short* vb_base = vbuf + (size_t)(b * 4 + kvh) * SK * 128;

  u16x8 k0[2], v0[2], k1[2], v1[2];

#define ATT_LOAD(kr, vr, kt1)                                                 \
  {                                                                           \
    _Pragma("unroll")                                                         \
    for (int i = 0; i < 2; ++i) {                                             \
      kr[i] = *(const u16x8*)&kb_base[(size_t)((kt1) + sr0 + 32 * i) * 128 + scc]; \
      vr[i] = *(const u16x8*)&vb_base[(size_t)((kt1) + sr0 + 32 * i) * 128 + scc]; \
    }                                                                         \
  }

#define ATT_STAGE(kr, vr)                                                     \
  {                                                                           \
    _Pragma("unroll")                                                         \
    for (int i = 0; i < 2; ++i) {                                             \
      int rr = sr0 + 32 * i;                                                  \
      *(u16x8*)&KsL[rr * 128 + (((scc >> 3) ^ (rr & 7)) << 3)] = kr[i];       \
      _Pragma("unroll")                                                       \
      for (int j = 0; j < 8; ++j)                                             \
        VTL[(scc + j) * 64 + ((((rr >> 3) ^ ((scc + j) >> 3)) & 7) << 3) + (rr & 7)] = vr[i][j]; \
    }                                                                         \
  }

  auto compute = [&]() {
    f32x4 sacc[4] = {};
    __builtin_amdgcn_s_setprio(1);
    #pragma unroll
    for (int ks = 0; ks < 4; ++ks) {
      #pragma unroll
      for (int ni = 0; ni < 4; ++ni) {
        int rr = ni * 16 + l16;
        bf16x8 kf = *(const bf16x8*)
            &KsL[rr * 128 + ((((ks * 32 + kb) >> 3) ^ (rr & 7)) << 3)];
        sacc[ni] = __builtin_amdgcn_mfma_f32_16x16x32_bf16(qf[ks], kf, sacc[ni], 0, 0, 0);
      }
    }
    __builtin_amdgcn_s_setprio(0);
    float pv[4][4], alpha[4];
    #pragma unroll
    for (int r = 0; r < 4; ++r) {
      float tm = fmaxf(fmaxf(sacc[0][r], sacc[1][r]), fmaxf(sacc[2][r], sacc[3][r]));
      #pragma unroll
      for (int off = 1; off < 16; off <<= 1) tm = fmaxf(tm, __shfl_xor(tm, off));
      float mn = fmaxf(mrow[r], tm);
      alpha[r] = __expf(mrow[r] - mn);
      float s = 0.f;
      #pragma unroll
      for (int ni = 0; ni < 4; ++ni) {
        float p = __expf(sacc[ni][r] - mn);
        pv[ni][r] = p; s += p;
      }
      #pragma unroll
      for (int off = 1; off < 16; off <<= 1) s += __shfl_xor(s, off);
      lrow[r] = lrow[r] * alpha[r] + s;
      mrow[r] = mn;
    }
    #pragma unroll
    for (int ni = 0; ni < 8; ++ni)
      #pragma unroll
      for (int r = 0; r < 4; ++r) oacc[ni][r] *= alpha[r];
    #pragma unroll
    for (int ni = 0; ni < 4; ++ni)
      #pragma unroll
      for (int r = 0; r < 4; ++r) {
        int row = r4 + r, col = ni * 16 + l16;
        PsL[wid * 1024 + row * 64 + ((((col >> 3) ^ (row & 7)) & 7) << 3) + (col & 7)]
            = f2bf(pv[ni][r]);
      }
    asm volatile("s_waitcnt lgkmcnt(0)" ::: "memory");
    __builtin_amdgcn_sched_barrier(0);
    __builtin_amdgcn_s_setprio(1);
    #pragma unroll
    for (int ks = 0; ks < 2; ++ks) {
      bf16x8 pf = *(const bf16x8*)
          &PsL[wid * 1024 + l16 * 64 + ((((ks * 32 + kb) >> 3) ^ (l16 & 7)) << 3)];
      #pragma unroll
      for (int ni = 0; ni < 8; ++ni) {
        int d = ni * 16 + l16;
        bf16x8 vf = *(const bf16x8*)
            &VTL[d * 64 + ((((ks * 32 + kb) >> 3) ^ ((d >> 3) & 7)) << 3)];
        oacc[ni] = __builtin_amdgcn_mfma_f32_16x16x32_bf16(pf, vf, oacc[ni], 0, 0, 0);
      }
    }
    __builtin_amdgcn_s_setprio(0);
  };

  ATT_LOAD(k0, v0, 0);
  for (int t = 0; t < 24; t += 2) {
    ATT_STAGE(k0, v0);
    ATT_LOAD(k1, v1, (t + 1) * 64);
    asm volatile("s_waitcnt lgkmcnt(0)" ::: "memory");
    __builtin_amdgcn_s_barrier();
    __builtin_amdgcn_sched_barrier(0);
    compute();
    __builtin_amdgcn_sched_barrier(0);
    __builtin_amdgcn_s_barrier();
    ATT_STAGE(k1, v1);
    if (t + 2 < 24) ATT_LOAD(k0, v0, (t + 2) * 64);
    asm volatile("s_waitcnt lgkmcnt(0)" ::: "memory");
    __builtin_amdgcn_s_barrier();
    __builtin_amdgcn_sched_barrier(0);
    compute();
    __builtin_amdgcn_sched_barrier(0);
    __builtin_amdgcn_s_barrier();
  }
#undef ATT_LOAD
#undef ATT_STAGE

  #pragma unroll
  for (int ni = 0; ni < 8; ++ni)
    #pragma unroll
    for (int r = 0; r < 4; ++r) {
      float val = oacc[ni][r] / lrow[r];
      size_t row = (size_t)b * 1024 + q0 + wid * 16 + r4 + r;
      o[row * 2048 + h * 128 + ni * 16 + l16] = f2bf(val);
    }
}

// act_silu over summed bf16 split-K partials.
__global__ __launch_bounds__(256) void act_silu2(
    const unsigned short* __restrict__ gu0, const unsigned short* __restrict__ gu1,
    unsigned short* __restrict__ act)
{
  int p = blockIdx.x;
  int c = threadIdx.x * 4;
  u16x4 g0 = *(const u16x4*)&gu0[(size_t)p * 2048 + c];
  u16x4 g1 = *(const u16x4*)&gu1[(size_t)p * 2048 + c];
  u16x4 u0 = *(const u16x4*)&gu0[(size_t)p * 2048 + 1024 + c];
  u16x4 u1 = *(const u16x4*)&gu1[(size_t)p * 2048 + 1024 + c];
  #pragma unroll
  for (int j = 0; j < 4; ++j) {
    float g = bf2f(g0[j]) + bf2f(g1[j]);
    float u = bf2f(u0[j]) + bf2f(u1[j]);
    float a = g / (1.f + __expf(-g)) * u;
    act[(size_t)p * 1024 + c + j] = f2bf(a);
  }
}

// combine over summed bf16 split-K partials.
__global__ __launch_bounds__(256) void moe_combine2(
    float* __restrict__ out, const unsigned short* __restrict__ eo0,
    const unsigned short* __restrict__ eo1,
    const int* __restrict__ token_slot, const float* __restrict__ topw)
{
  int t = blockIdx.x;
  int c = threadIdx.x * 8;
  int s0 = token_slot[2 * t], s1 = token_slot[2 * t + 1];
  float w0 = topw[2 * t], w1 = topw[2 * t + 1];
  u16x8 a0 = *(const u16x8*)&eo0[(size_t)s0 * 2048 + c];
  u16x8 a1 = *(const u16x8*)&eo1[(size_t)s0 * 2048 + c];
  u16x8 b0 = *(const u16x8*)&eo0[(size_t)s1 * 2048 + c];
  u16x8 b1 = *(const u16x8*)&eo1[(size_t)s1 * 2048 + c];
  #pragma unroll
  for (int j0 = 0; j0 < 8; j0 += 4) {
    float4 v = *(const float4*)&out[(size_t)t * 2048 + c + j0];
    v.x += w0 * (bf2f(a0[j0+0]) + bf2f(a1[j0+0])) + w1 * (bf2f(b0[j0+0]) + bf2f(b1[j0+0]));
    v.y += w0 * (bf2f(a0[j0+1]) + bf2f(a1[j0+1])) + w1 * (bf2f(b0[j0+1]) + bf2f(b1[j0+1]));
    v.z += w0 * (bf2f(a0[j0+2]) + bf2f(a1[j0+2])) + w1 * (bf2f(b0[j0+2]) + bf2f(b1[j0+2]));
    v.w += w0 * (bf2f(a0[j0+3]) + bf2f(a1[j0+3])) + w1 * (bf2f(b0[j0+3]) + bf2f(b1[j0+3]));
    *(float4*)&out[(size_t)t * 2048 + c + j0] = v;
  }
}

// ---------------------------------------------------------------------------
extern "C" void kernel_launch(void* const* d_in, const int* in_sizes, int n_in,
                              void* d_out, int out_size, void* d_ws, size_t ws_size,
                              hipStream_t stream)
{
  const float* hidden  = (const float*)d_in[0];
  const float* enc     = (const float*)d_in[1];
  const float* img_cos = (const float*)d_in[2];
  const float* img_sin = (const float*)d_in[3];
  const float* txt_cos = (const float*)d_in[4];
  const float* txt_sin = (const float*)d_in[5];
  const float* norm1_w = (const float*)d_in[6];
  const float* norm2_w = (const float*)d_in[7];
  const float* wq      = (const float*)d_in[8];
  const float* wk      = (const float*)d_in[9];
  const float* wv      = (const float*)d_in[10];
  const float* wk_txt  = (const float*)d_in[11];
  const float* wv_txt  = (const float*)d_in[12];
  const float* wo      = (const float*)d_in[13];
  const float* q_norm_w       = (const float*)d_in[14];
  const float* k_norm_w       = (const float*)d_in[15];
  const float* added_k_norm_w = (const float*)d_in[16];
  const float* router_w       = (const float*)d_in[17];
  const float* gate_up_proj   = (const float*)d_in[18];
  const float* down_proj      = (const float*)d_in[19];
  float* out = (float*)d_out;

  char* ws = (char*)d_ws;
  size_t off = 0;
  auto alloc = [&](size_t bytes) {
    void* p = ws + off;
    off += (bytes + 255) & ~(size_t)255;
    return p;
  };
  unsigned short* wqkvT  = (unsigned short*)alloc(3072ULL * 2048 * 2);
  unsigned short* wkvtT  = (unsigned short*)alloc(1024ULL * 2048 * 2);
  unsigned short* woT    = (unsigned short*)alloc(2048ULL * 2048 * 2);
  unsigned short* gupT   = (unsigned short*)alloc(8ULL * 2048 * 2048 * 2);
  unsigned short* dnT    = (unsigned short*)alloc(8ULL * 2048 * 1024 * 2);
  unsigned short* x_bf   = (unsigned short*)alloc(2048ULL * 2048 * 2);
  unsigned short* enc_bf = (unsigned short*)alloc(1024ULL * 2048 * 2);
  unsigned short* gu0 = (unsigned short*)alloc(4096ULL * 2048 * 2);
  unsigned short* gu1 = (unsigned short*)alloc(4096ULL * 2048 * 2);
  unsigned short* qb   = (unsigned short*)alloc(2048ULL * 2048 * 2);
  unsigned short* kbuf = (unsigned short*)alloc(2ULL * 4 * 1536 * 128 * 2);
  unsigned short* vbuf = (unsigned short*)alloc(2ULL * 4 * 1536 * 128 * 2);
  unsigned short* obuf = (unsigned short*)alloc(2048ULL * 2048 * 2);
  unsigned short* act  = obuf;
  unsigned short* xt   = (unsigned short*)alloc(2048ULL * 2048 * 2);
  int*   ctrl  = (int*)alloc(64 * sizeof(int));
  int*   topi  = (int*)alloc(4096 * 4);
  float* topw  = (float*)alloc(4096 * 4);
  int*   tslot = (int*)alloc(4096 * 4);
  int*   ptok  = (int*)alloc(4096 * 4);
  unsigned short* zbuf = (unsigned short*)alloc(256);
  int* counts = ctrl, * offsets = ctrl + 16;

  hipMemsetAsync(ctrl, 0, 64, stream);
  hipMemsetAsync(zbuf, 0, 256, stream);

  const float scale = 0.08838834764831845f;  // 1/sqrt(128)

  CvtJobs jb;
  jb.src[0] = wq;     jb.dst[0] = wqkvT;                  jb.K[0] = 2048; jb.N[0] = 2048;
  jb.src[1] = wk;     jb.dst[1] = wqkvT + 2048ULL * 2048; jb.K[1] = 2048; jb.N[1] = 512;
  jb.src[2] = wv;     jb.dst[2] = wqkvT + 2560ULL * 2048; jb.K[2] = 2048; jb.N[2] = 512;
  jb.src[3] = wk_txt; jb.dst[3] = wkvtT;                  jb.K[3] = 2048; jb.N[3] = 512;
  jb.src[4] = wv_txt; jb.dst[4] = wkvtT + 512ULL * 2048;  jb.K[4] = 2048; jb.N[4] = 512;
  jb.src[5] = wo;     jb.dst[5] = woT;                    jb.K[5] = 2048; jb.N[5] = 2048;
  jb.src[6] = gate_up_proj; jb.dst[6] = gupT;             jb.K[6] = 2048; jb.N[6] = 2048;
  jb.src[7] = down_proj;    jb.dst[7] = dnT;              jb.K[7] = 1024; jb.N[7] = 2048;
  jb.off[0] = 0;    jb.off[1] = 512;  jb.off[2] = 640;  jb.off[3] = 768;
  jb.off[4] = 896;  jb.off[5] = 1024; jb.off[6] = 1536; jb.off[7] = 5632;
  jb.off[8] = 7680;
  // convert (7680 blocks) + pre_norm tail (3072 blocks)
  convert_all<<<10752, 256, 0, stream>>>(jb, hidden, norm1_w, x_bf, enc, enc_bf);

  Epi ep;
  ep.qb = qb; ep.kbuf = kbuf; ep.vbuf = vbuf;
  ep.q_nw = q_norm_w; ep.k_nw = k_norm_w; ep.kt_nw = added_k_norm_w;
  ep.icos = img_cos; ep.isin = img_sin; ep.tcos = txt_cos; ep.tsin = txt_sin;
  ep.scale = scale;

  // merged qkv (384 blocks, mode 1) + kvt (64 blocks, mode 2)
  gemm_bb<<<448, 256, 0, stream>>>(x_bf, wqkvT, nullptr, nullptr, 2048, 3072, 2048, 1, ep,
                                   enc_bf, wkvtT, 1024, 1024, 384);

  attn_kernel<<<256, 512, 0, stream>>>(qb, kbuf, vbuf, obuf);

  gemm_bb<<<256, 256, 0, stream>>>(obuf, woT, out, hidden, 2048, 2048, 2048, 0, ep,
                                   nullptr, nullptr, 0, 0, 0);

  rmsnorm_router<<<2048, 256, 0, stream>>>(out, norm2_w, xt, router_w,
                                           topi, topw, counts);
  route_build<<<1, 256, 0, stream>>>(counts, offsets, topi, ptok, tslot);

  gemm_moe_256sk<<<1024, 512, 0, stream>>>(xt, gupT, gu0, gu1,
                                           counts, offsets, ptok, zbuf, 1, 2048, 2048);
  act_silu2<<<4096, 256, 0, stream>>>(gu0, gu1, act);
  gemm_moe_256sk<<<1024, 512, 0, stream>>>(act, dnT, gu0, gu1,
                                           counts, offsets, ptok, zbuf, 0, 1024, 2048);
  moe_combine2<<<2048, 256, 0, stream>>>(out, gu0, gu1, tslot, topw);
}